// Round 10
// baseline (210.995 us; speedup 1.0000x reference)
//
#include <hip/hip_runtime.h>
#include <hip/hip_bf16.h>
#include <hip/hip_fp16.h>

typedef _Float16 h8 __attribute__((ext_vector_type(8)));
typedef _Float16 h2 __attribute__((ext_vector_type(2)));
typedef unsigned short us8 __attribute__((ext_vector_type(8)));
typedef float f4 __attribute__((ext_vector_type(4)));

#define NH 8
#define DH 64
#define NPIX 1024
#define CIN 64
#define NBH 64
// 512 (ref scale) * log2(e): logits come out in base-2 units
#define QSCALE (512.0f * 1.44269504f)
#define LOSCALE 2048.0f
#define INV_LOSCALE (1.0f / 2048.0f)
#define DTHR 12.0f

__device__ __forceinline__ void gload_lds16(const void* g, void* lds) {
  __builtin_amdgcn_global_load_lds(
      (const __attribute__((address_space(1))) void*)g,
      (__attribute__((address_space(3))) void*)lds, 16, 0, 0);
}

__device__ __forceinline__ float fexp2(float x) {
#if __has_builtin(__builtin_amdgcn_exp2f)
  return __builtin_amdgcn_exp2f(x);
#else
  return exp2f(x);
#endif
}

__device__ __forceinline__ unsigned pk16(float a, float b) {
  auto r = __builtin_amdgcn_cvt_pkrtz(a, b);   // __fp16 ext_vector(2)
  union { decltype(r) h; unsigned u; } x;
  x.h = r;
  return x.u;
}

__device__ __forceinline__ f4 max4(f4 a, f4 b) {
  f4 r;
  r[0] = fmaxf(a[0], b[0]); r[1] = fmaxf(a[1], b[1]);
  r[2] = fmaxf(a[2], b[2]); r[3] = fmaxf(a[3], b[3]);
  return r;
}

// ---------------- QKV projection via compensated fp16 MFMA ----------------
// Internal W/X split keeps LOSCALE (W resid ~1e-5 would be fp16-subnormal);
// OUTPUT residuals Ql/Kl are stored UNSCALED (normal range) so attn can
// accumulate compensation MFMAs directly into the main accumulator.
__global__ __launch_bounds__(256) void qkv_mfma(
    const float* __restrict__ x, const float* __restrict__ wqkv,
    _Float16* __restrict__ Qh, _Float16* __restrict__ Ql,
    _Float16* __restrict__ Kh, _Float16* __restrict__ Kl,
    _Float16* __restrict__ Vv) {
  __shared__ __align__(16) char QS[49152];
  char* Wh = QS;
  char* Wl = QS + 16384;
  char* Xh = QS + 32768;
  char* Xl = QS + 40960;

  const int tid = threadIdx.x;
  const int lane = tid & 63;
  const int w = tid >> 6;
  const int c = lane & 15;
  const int g = lane >> 4;
  const int o0 = blockIdx.x * 128;
  const int p0 = blockIdx.y * 64;
  const int b = blockIdx.z;

  #pragma unroll
  for (int it = 0; it < 4; ++it) {
    int task = tid + it * 256;
    int oct = task & 7, o = task >> 3;
    const f4* wr = (const f4*)(wqkv + (size_t)(o0 + o) * CIN + oct * 8);
    f4 wa = wr[0], wb = wr[1];
    h8 hi, lo;
    #pragma unroll
    for (int e = 0; e < 8; ++e) {
      float v = e < 4 ? wa[e] : wb[e - 4];
      _Float16 h = (_Float16)v;
      hi[e] = h;
      lo[e] = (_Float16)((v - (float)h) * LOSCALE);
    }
    int byo = o * 128 + ((oct ^ (o & 7)) << 4);
    *(h8*)(Wh + byo) = hi;
    *(h8*)(Wl + byo) = lo;
  }
  // X transposed via c-pair-packed u32 (conflict-free banks)
  {
    int kp = tid & 31;
    int pgrp = tid >> 5;
    const float* xr0 = x + ((size_t)b * CIN + 2 * kp) * NPIX + p0 + pgrp * 8;
    const float* xr1 = xr0 + NPIX;
    f4 a0 = *(const f4*)xr0, a1 = *(const f4*)(xr0 + 4);
    f4 b0 = *(const f4*)xr1, b1 = *(const f4*)(xr1 + 4);
    int oct = kp >> 2;
    int slot4 = (kp & 3) * 4;
    #pragma unroll
    for (int e = 0; e < 8; ++e) {
      float v0 = e < 4 ? a0[e] : a1[e - 4];
      float v1 = e < 4 ? b0[e] : b1[e - 4];
      _Float16 h0 = (_Float16)v0, h1 = (_Float16)v1;
      float l0f = (v0 - (float)h0) * LOSCALE;
      float l1f = (v1 - (float)h1) * LOSCALE;
      int p = pgrp * 8 + e;
      int byo = p * 128 + ((oct ^ (p & 7)) << 4) + slot4;
      union { h2 h; unsigned u; } uh, ul;
      uh.h[0] = h0; uh.h[1] = h1;
      ul.h[0] = (_Float16)l0f; ul.h[1] = (_Float16)l1f;
      *(unsigned*)(Xh + byo) = uh.u;
      *(unsigned*)(Xl + byo) = ul.u;
    }
  }
  __syncthreads();

  f4 zf = {0.f, 0.f, 0.f, 0.f};
  f4 acc[2][4], cor[2][4];
  #pragma unroll
  for (int oi = 0; oi < 2; ++oi)
    #pragma unroll
    for (int pi = 0; pi < 4; ++pi) { acc[oi][pi] = zf; cor[oi][pi] = zf; }

  const int ob = w * 32;
  #pragma unroll
  for (int kh = 0; kh < 2; ++kh) {
    h8 ah[2], al[2], bh[4], bl[4];
    #pragma unroll
    for (int oi = 0; oi < 2; ++oi) {
      int orow = ob + ((c >> 2) << 3) + (c & 3) + oi * 4;
      int ch = (((kh * 4 + g) ^ (orow & 7)) << 4);
      ah[oi] = *(const h8*)(Wh + orow * 128 + ch);
      al[oi] = *(const h8*)(Wl + orow * 128 + ch);
    }
    #pragma unroll
    for (int pi = 0; pi < 4; ++pi) {
      int prow = pi * 16 + c;
      int ch = (((kh * 4 + g) ^ (prow & 7)) << 4);
      bh[pi] = *(const h8*)(Xh + prow * 128 + ch);
      bl[pi] = *(const h8*)(Xl + prow * 128 + ch);
    }
    __builtin_amdgcn_s_setprio(1);
    #pragma unroll
    for (int oi = 0; oi < 2; ++oi)
      #pragma unroll
      for (int pi = 0; pi < 4; ++pi) {
        acc[oi][pi] = __builtin_amdgcn_mfma_f32_16x16x32_f16(ah[oi], bh[pi], acc[oi][pi], 0, 0, 0);
        cor[oi][pi] = __builtin_amdgcn_mfma_f32_16x16x32_f16(ah[oi], bl[pi], cor[oi][pi], 0, 0, 0);
        cor[oi][pi] = __builtin_amdgcn_mfma_f32_16x16x32_f16(al[oi], bh[pi], cor[oi][pi], 0, 0, 0);
      }
    __builtin_amdgcn_s_setprio(0);
  }

  const int part = o0 >> 9;
  const float scl = part == 0 ? QSCALE : 1.0f;
  _Float16* dsth = part == 0 ? Qh : (part == 1 ? Kh : Vv);
  _Float16* dstl = part == 0 ? Ql : (part == 1 ? Kl : nullptr);
  #pragma unroll
  for (int pi = 0; pi < 4; ++pi) {
    int obase = o0 + ob + 8 * g;
    int h = (obase >> 6) & 7;
    int d = obase & 63;
    int p_abs = p0 + pi * 16 + c;
    size_t off = (((size_t)(b * NH + h)) * NPIX + p_abs) * DH + d;
    h8 hv, lv;
    #pragma unroll
    for (int oi = 0; oi < 2; ++oi)
      #pragma unroll
      for (int reg = 0; reg < 4; ++reg) {
        float v = (acc[oi][pi][reg] + cor[oi][pi][reg] * INV_LOSCALE) * scl;
        _Float16 hh = (_Float16)v;
        hv[oi * 4 + reg] = hh;
        lv[oi * 4 + reg] = (_Float16)(v - (float)hh);   // UNSCALED residual
      }
    *(h8*)(dsth + off) = hv;
    if (dstl) *(h8*)(dstl + off) = lv;
  }
}

// ---------------- fused MFMA attention: 8 waves, split-j halves ----------
// Block: one (b,h) x 128 rows, 512 threads. Waves 0-3 (grp0): j-tiles 0-7;
// waves 4-7 (grp1): j-tiles 8-15. Single-buffered K/V per group.
// LDS (72KB): KH[grp] 0..16K | KL[grp] 16K..32K | VB[grp] 32K..48K |
//             SP 48K..64K (2KB/wave) | LHc 64K..72K ([32 k][128] f16).
// Prologue: rel_h->KH0, rel_w->KL0, LWT f16[128][64]->VB. Epilogue: merge.
__global__ __launch_bounds__(512, 4) void attn_mfma(
    const _Float16* __restrict__ Qh, const _Float16* __restrict__ Ql,
    const _Float16* __restrict__ Kh, const _Float16* __restrict__ Kl,
    const _Float16* __restrict__ V,
    const float* __restrict__ rel_h, const float* __restrict__ rel_w,
    float* __restrict__ out) {
  __shared__ __align__(16) char SMem[73728];
  const int tid = threadIdx.x;
  const int lane = tid & 63;
  const int wu = tid >> 6;        // 0..7
  const int lw = wu & 3;          // wave within group
  const int grp = wu >> 2;        // j-half
  const int c = lane & 15;
  const int g = lane >> 4;
  const int bx = blockIdx.x;
  const int bh = ((bx & 7) << 3) | ((bx >> 3) & 7);
  const int i0 = (bx >> 6) << 7;
  const int swz = (c & 7) << 4;

  char* KHb = SMem + grp * 8192;
  char* KLb = SMem + 16384 + grp * 8192;
  char* VBb = SMem + 32768 + grp * 8192;
  char* SPw = SMem + 49152 + wu * 2048;
  _Float16* LHc = (_Float16*)(SMem + 65536);
  _Float16* LWT = (_Float16*)(SMem + 32768);   // prologue temp 16KB

  const _Float16* Qhg = Qh + (size_t)bh * NPIX * DH;
  const _Float16* Qlg = Ql + (size_t)bh * NPIX * DH;
  const _Float16* Khg = Kh + (size_t)bh * NPIX * DH;
  const _Float16* Klg = Kl + (size_t)bh * NPIX * DH;
  const _Float16* Vg  = V  + (size_t)bh * NPIX * DH;

  // Q fragments (B operand: col = i = base + c)
  const h8* Qr0h = (const h8*)(Qhg + (size_t)(i0 + lw * 32 + c) * DH);
  const h8* Qr0l = (const h8*)(Qlg + (size_t)(i0 + lw * 32 + c) * DH);
  const h8* Qr1h = (const h8*)(Qhg + (size_t)(i0 + lw * 32 + 16 + c) * DH);
  const h8* Qr1l = (const h8*)(Qlg + (size_t)(i0 + lw * 32 + 16 + c) * DH);
  h8 q0h[2] = {Qr0h[g], Qr0h[4 + g]};
  h8 q0l[2] = {Qr0l[g], Qr0l[4 + g]};
  h8 q1h[2] = {Qr1h[g], Qr1h[4 + g]};
  h8 q1l[2] = {Qr1l[g], Qr1l[4 + g]};

  // K staging offsets (pre-swizzled global source, linear LDS dest)
  const int s0i = lw * 128 + lane;
  const int s1i = s0i + 64;
  const int ko0 = (s0i >> 3) * 128 + (((s0i & 7) ^ ((s0i >> 3) & 7)) << 4);
  const int ko1 = (s1i >> 3) * 128 + (((s1i & 7) ^ ((s1i >> 3) & 7)) << 4);
  const int ltid = tid & 255;
  const int jp = ltid & 31, dd = ltid >> 5;

  // ---- stage rel tables (512 threads, one pass) ----
  {
    int oct = tid & 7, s = tid >> 3;
    int ss = s < 63 ? s : 62;
    const float* sh = rel_h + (size_t)ss * DH + oct * 8;
    const float* sw = rel_w + (size_t)ss * DH + oct * 8;
    h8 hh, ww;
    #pragma unroll
    for (int e = 0; e < 8; ++e) {
      hh[e] = (_Float16)sh[e];
      ww[e] = (_Float16)sw[e];
    }
    int byo = s * 128 + ((oct ^ (s & 7)) << 4);
    *(h8*)(SMem + byo) = hh;
    *(h8*)(SMem + 16384 + byo) = ww;
  }
  __syncthreads();

  // ---- lh/lw tables via swapped MFMA (lo folded into same acc) ----
  const int yi = (i0 + lw * 32) >> 5;
  f4 zf = {0.f, 0.f, 0.f, 0.f};
  #pragma unroll
  for (int rs = 0; rs < 2; ++rs) {
    f4 lhD[4], lwD[4];
    #pragma unroll
    for (int st = 0; st < 4; ++st) { lhD[st] = zf; lwD[st] = zf; }
    #pragma unroll
    for (int kh = 0; kh < 2; ++kh) {
      h8 bq = rs ? q1h[kh] : q0h[kh];
      h8 bl = rs ? q1l[kh] : q0l[kh];
      #pragma unroll
      for (int st = 0; st < 4; ++st) {
        int srow = st * 16 + c;
        int chb = srow * 128 + (((kh * 4 + g) ^ (srow & 7)) << 4);
        h8 ra = *(const h8*)(SMem + chb);
        h8 wa = *(const h8*)(SMem + 16384 + chb);
        lhD[st] = __builtin_amdgcn_mfma_f32_16x16x32_f16(ra, bq, lhD[st], 0, 0, 0);
        lhD[st] = __builtin_amdgcn_mfma_f32_16x16x32_f16(ra, bl, lhD[st], 0, 0, 0);
        lwD[st] = __builtin_amdgcn_mfma_f32_16x16x32_f16(wa, bq, lwD[st], 0, 0, 0);
        lwD[st] = __builtin_amdgcn_mfma_f32_16x16x32_f16(wa, bl, lwD[st], 0, 0, 0);
      }
    }
    int lrow = lw * 32 + rs * 16 + c;
    #pragma unroll
    for (int st = 0; st < 4; ++st)
      #pragma unroll
      for (int reg = 0; reg < 4; ++reg) {
        int s = st * 16 + 4 * g + reg;
        int k = s - 31 + yi;
        if (k >= 0 && k < 32) LHc[k * 128 + lrow] = (_Float16)lhD[st][reg];
        LWT[lrow * 64 + s] = (_Float16)lwD[st][reg];
      }
  }
  __syncthreads();

  float lwp0[8], lwp1[8];
  #pragma unroll
  for (int jbp = 0; jbp < 2; ++jbp)
    #pragma unroll
    for (int reg = 0; reg < 4; ++reg) {
      lwp0[jbp * 4 + reg] = (float)LWT[(lw * 32 + c) * 64 + 31 + jbp * 16 + 4 * g + reg - c];
      lwp1[jbp * 4 + reg] = (float)LWT[(lw * 32 + 16 + c) * 64 + 31 + jbp * 16 + 4 * g + reg - 16 - c];
    }
  __syncthreads();

  // ---- initial stage: tile tg0 = grp*8 ----
  {
    const int tg0 = grp << 3;
    gload_lds16((const char*)Khg + tg0 * 8192 + ko0, KHb + lw * 2048);
    gload_lds16((const char*)Khg + tg0 * 8192 + ko1, KHb + lw * 2048 + 1024);
    gload_lds16((const char*)Klg + tg0 * 8192 + ko0, KLb + lw * 2048);
    gload_lds16((const char*)Klg + tg0 * 8192 + ko1, KLb + lw * 2048 + 1024);
    const h8* vr = (const h8*)(Vg + (size_t)(tg0 * 64 + 2 * jp) * DH);
    h8 v0 = vr[dd], v1 = vr[8 + dd];
    us8 u0 = *(const us8*)&v0, u1 = *(const us8*)&v1;
    #pragma unroll
    for (int e = 0; e < 8; ++e) {
      int d = dd * 8 + e;
      unsigned int val = (unsigned int)u0[e] | ((unsigned int)u1[e] << 16);
      *(unsigned int*)(VBb + d * 128 + (((jp >> 2) ^ (d & 7)) << 4) + (jp & 3) * 4) = val;
    }
  }
  __syncthreads();

  float m0 = -1e30f, m1 = -1e30f, lp0 = 0.f, lp1 = 0.f;
  f4 o0_[4], o1_[4];
  #pragma unroll
  for (int dt = 0; dt < 4; ++dt) { o0_[dt] = zf; o1_[dt] = zf; }

  #pragma unroll 1
  for (int t = 0; t < 8; ++t) {
    const int tg = (grp << 3) + t;
    const bool pre = t < 7;
    h8 v0n = {}, v1n = {};
    if (pre) {   // issue next-tile V global loads early
      const h8* vr = (const h8*)(Vg + (size_t)((tg + 1) * 64 + 2 * jp) * DH);
      v0n = vr[dd];
      v1n = vr[8 + dd];
    }

    // ---- QK^T swapped, compensation folded into same accumulator ----
    f4 s0[4], s1[4];
    #pragma unroll
    for (int jb = 0; jb < 4; ++jb) { s0[jb] = zf; s1[jb] = zf; }
    #pragma unroll
    for (int kh = 0; kh < 2; ++kh) {
      h8 b0h = q0h[kh], b0l = q0l[kh], b1h = q1h[kh], b1l = q1l[kh];
      #pragma unroll
      for (int jb = 0; jb < 4; ++jb) {
        int chb = (jb * 16 + c) * 128 + (((kh * 4 + g) ^ (c & 7)) << 4);
        h8 ah = *(const h8*)(KHb + chb);
        h8 al = *(const h8*)(KLb + chb);
        __builtin_amdgcn_s_setprio(1);
        s0[jb] = __builtin_amdgcn_mfma_f32_16x16x32_f16(ah, b0h, s0[jb], 0, 0, 0);
        s0[jb] = __builtin_amdgcn_mfma_f32_16x16x32_f16(al, b0h, s0[jb], 0, 0, 0);
        s0[jb] = __builtin_amdgcn_mfma_f32_16x16x32_f16(ah, b0l, s0[jb], 0, 0, 0);
        s1[jb] = __builtin_amdgcn_mfma_f32_16x16x32_f16(ah, b1h, s1[jb], 0, 0, 0);
        s1[jb] = __builtin_amdgcn_mfma_f32_16x16x32_f16(al, b1h, s1[jb], 0, 0, 0);
        s1[jb] = __builtin_amdgcn_mfma_f32_16x16x32_f16(ah, b1l, s1[jb], 0, 0, 0);
        __builtin_amdgcn_s_setprio(0);
      }
    }

    auto finish = [&](f4* s_, const float* lwp, float& m_s, float& lp,
                      f4* o_, int rs) {
      int rr = lw * 32 + rs * 16 + c;
      float lh0 = (float)LHc[(2 * tg) * 128 + rr];
      float lh1 = (float)LHc[(2 * tg + 1) * 128 + rr];
      #pragma unroll
      for (int jb = 0; jb < 4; ++jb) {
        float lhv = (jb >> 1) ? lh1 : lh0;
        #pragma unroll
        for (int reg = 0; reg < 4; ++reg)
          s_[jb][reg] += lwp[(jb & 1) * 4 + reg] + lhv;
      }
      f4 ef = max4(max4(s_[0], s_[1]), max4(s_[2], s_[3]));
      float mx = fmaxf(fmaxf(ef[0], ef[1]), fmaxf(ef[2], ef[3]));
      mx = fmaxf(mx, __shfl_xor(mx, 16, 64));
      mx = fmaxf(mx, __shfl_xor(mx, 32, 64));
      bool sk = mx <= m_s + DTHR;
      if (!__all(sk)) {
        float mn = fmaxf(m_s, mx);
        float corr = fexp2(m_s - mn);
        m_s = mn;
        lp *= corr;
        #pragma unroll
        for (int dt = 0; dt < 4; ++dt)
          #pragma unroll
          for (int reg = 0; reg < 4; ++reg)
            o_[dt][reg] *= corr;
      }
      float sum = 0.f;
      char* pbse = SPw + c * 128;
      #pragma unroll
      for (int jb = 0; jb < 4; ++jb) {
        f4 p;
        #pragma unroll
        for (int reg = 0; reg < 4; ++reg) {
          p[reg] = fexp2(s_[jb][reg] - m_s);
          sum += p[reg];
        }
        unsigned long long u = (unsigned long long)pk16(p[0], p[1]) |
                               ((unsigned long long)pk16(p[2], p[3]) << 32);
        *(unsigned long long*)(pbse + ((jb * 32 + 8 * g) ^ swz)) = u;
      }
      lp += sum;
    };

    finish(s0, lwp0, m0, lp0, o0_, 0);
    __syncthreads();            // all waves done reading K(t)
    if (pre) {                  // restage K(t+1) into the single K buffer
      gload_lds16((const char*)Khg + (tg + 1) * 8192 + ko0, KHb + lw * 2048);
      gload_lds16((const char*)Khg + (tg + 1) * 8192 + ko1, KHb + lw * 2048 + 1024);
      gload_lds16((const char*)Klg + (tg + 1) * 8192 + ko0, KLb + lw * 2048);
      gload_lds16((const char*)Klg + (tg + 1) * 8192 + ko1, KLb + lw * 2048 + 1024);
    }

    // ---- PV rowset0 (A=V, B=P), cache V fragments ----
    h8 vbr[2][4];
    #pragma unroll
    for (int kh = 0; kh < 2; ++kh) {
      int och = ((kh * 4 + g) ^ (c & 7)) << 4;
      h8 pb = *(const h8*)(SPw + c * 128 + och);
      __builtin_amdgcn_s_setprio(1);
      #pragma unroll
      for (int dt = 0; dt < 4; ++dt) {
        vbr[kh][dt] = *(const h8*)(VBb + (dt * 16 + c) * 128 + och);
        o0_[dt] = __builtin_amdgcn_mfma_f32_16x16x32_f16(vbr[kh][dt], pb, o0_[dt], 0, 0, 0);
      }
      __builtin_amdgcn_s_setprio(0);
    }

    finish(s1, lwp1, m1, lp1, o1_, 1);
    __builtin_amdgcn_wave_barrier();

    #pragma unroll
    for (int kh = 0; kh < 2; ++kh) {
      int och = ((kh * 4 + g) ^ (c & 7)) << 4;
      h8 pb = *(const h8*)(SPw + c * 128 + och);
      __builtin_amdgcn_s_setprio(1);
      #pragma unroll
      for (int dt = 0; dt < 4; ++dt)
        o1_[dt] = __builtin_amdgcn_mfma_f32_16x16x32_f16(vbr[kh][dt], pb, o1_[dt], 0, 0, 0);
      __builtin_amdgcn_s_setprio(0);
    }

    __syncthreads();            // all waves done reading V(t); K(t+1) landed
    if (pre) {                  // write prefetched V(t+1)
      us8 u0 = *(const us8*)&v0n, u1 = *(const us8*)&v1n;
      #pragma unroll
      for (int e = 0; e < 8; ++e) {
        int d = dd * 8 + e;
        unsigned int val = (unsigned int)u0[e] | ((unsigned int)u1[e] << 16);
        *(unsigned int*)(VBb + d * 128 + (((jp >> 2) ^ (d & 7)) << 4) + (jp & 3) * 4) = val;
      }
    }
  }

  // ---- merge epilogue: pair (lw, lw+4) over j-halves ----
  __syncthreads();
  {
    // exchange: write m,l + the o-half the PARTNER merges (stride 21 floats)
    float* exw = (float*)SMem + ((size_t)wu * 64 + lane) * 21;
    exw[0] = m0; exw[1] = lp0; exw[2] = m1; exw[3] = lp1;
    int wb = grp ? 0 : 2;   // write half I do NOT merge
    #pragma unroll
    for (int k = 0; k < 2; ++k)
      #pragma unroll
      for (int reg = 0; reg < 4; ++reg) {
        exw[4 + k * 4 + reg] = o0_[wb + k][reg];
        exw[12 + k * 4 + reg] = o1_[wb + k][reg];
      }
  }
  __syncthreads();
  float r0, r1;
  f4 om0[2], om1[2];
  const int mybase = grp * 2;
  {
    const float* exp_ = (const float*)SMem + ((size_t)(wu ^ 4) * 64 + lane) * 21;
    float pm0 = exp_[0], plp0 = exp_[1], pm1 = exp_[2], plp1 = exp_[3];
    float M0 = fmaxf(m0, pm0);
    float ca0 = fexp2(m0 - M0), cb0 = fexp2(pm0 - M0);
    float M1 = fmaxf(m1, pm1);
    float ca1 = fexp2(m1 - M1), cb1 = fexp2(pm1 - M1);
    float L0 = lp0 * ca0 + plp0 * cb0;
    float L1 = lp1 * ca1 + plp1 * cb1;
    L0 += __shfl_xor(L0, 16, 64);
    L0 += __shfl_xor(L0, 32, 64);
    L1 += __shfl_xor(L1, 16, 64);
    L1 += __shfl_xor(L1, 32, 64);
    r0 = __builtin_amdgcn_rcpf(L0);
    r1 = __builtin_amdgcn_rcpf(L1);
    #pragma unroll
    for (int k = 0; k < 2; ++k)
      #pragma unroll
      for (int reg = 0; reg < 4; ++reg) {
        om0[k][reg] = o0_[mybase + k][reg] * ca0 + exp_[4 + k * 4 + reg] * cb0;
        om1[k][reg] = o1_[mybase + k][reg] * ca1 + exp_[12 + k * 4 + reg] * cb1;
      }
  }
  __syncthreads();
  // OT transpose [64 d][128 rows] f32 (32KB over K areas) + store
  float* OT = (float*)SMem;
  #pragma unroll
  for (int k = 0; k < 2; ++k)
    #pragma unroll
    for (int reg = 0; reg < 4; ++reg) {
      int d = (mybase + k) * 16 + 4 * g + reg;
      int sw = (d & 7) << 3;
      int il0 = lw * 32 + c;
      OT[d * 128 + (il0 ^ sw)] = om0[k][reg] * r0;
      OT[d * 128 + ((il0 + 16) ^ sw)] = om1[k][reg] * r1;
    }
  __syncthreads();
  #pragma unroll
  for (int it = 0; it < 4; ++it) {
    int task = tid + it * 512;
    int rq = task & 31, d = task >> 5;
    f4 vv = *(const f4*)&OT[d * 128 + ((rq * 4) ^ ((d & 7) << 3))];
    *(f4*)(out + (((size_t)bh * 64 + d) << 10) + i0 + rq * 4) = vv;
  }
}

extern "C" void kernel_launch(void* const* d_in, const int* in_sizes, int n_in,
                              void* d_out, int out_size, void* d_ws, size_t ws_size,
                              hipStream_t stream) {
  const float* x  = (const float*)d_in[0];
  const float* wq = (const float*)d_in[1];
  const float* rh = (const float*)d_in[2];
  const float* rw = (const float*)d_in[3];
  float* out = (float*)d_out;

  const size_t sz = (size_t)NBH * NPIX * DH;
  _Float16* Qh = (_Float16*)d_ws;
  _Float16* Ql = Qh + sz;
  _Float16* Kh = Ql + sz;
  _Float16* Kl = Kh + sz;
  _Float16* V  = Kl + sz;

  qkv_mfma<<<dim3(12, 16, 8), 256, 0, stream>>>(x, wq, Qh, Ql, Kh, Kl, V);
  attn_mfma<<<dim3(512), 512, 0, stream>>>(Qh, Ql, Kh, Kl, V, rh, rw, out);
}

// Round 11
// 78.851 us; speedup vs baseline: 2.6759x; 2.6759x over previous
//
#include <hip/hip_runtime.h>
#include <hip/hip_bf16.h>
#include <hip/hip_fp16.h>

typedef _Float16 h8 __attribute__((ext_vector_type(8)));
typedef _Float16 h2 __attribute__((ext_vector_type(2)));
typedef unsigned short us8 __attribute__((ext_vector_type(8)));
typedef float f4 __attribute__((ext_vector_type(4)));

#define NH 8
#define DH 64
#define NPIX 1024
#define CIN 64
#define NBH 64
// 512 (ref scale) * log2(e): logits come out in base-2 units
#define QSCALE (512.0f * 1.44269504f)
#define LOSCALE 2048.0f
#define INV_LOSCALE (1.0f / 2048.0f)
#define DTHR 12.0f

__device__ __forceinline__ void gload_lds16(const void* g, void* lds) {
  __builtin_amdgcn_global_load_lds(
      (const __attribute__((address_space(1))) void*)g,
      (__attribute__((address_space(3))) void*)lds, 16, 0, 0);
}

__device__ __forceinline__ float fexp2(float x) {
#if __has_builtin(__builtin_amdgcn_exp2f)
  return __builtin_amdgcn_exp2f(x);
#else
  return exp2f(x);
#endif
}

__device__ __forceinline__ unsigned pk16(float a, float b) {
  auto r = __builtin_amdgcn_cvt_pkrtz(a, b);   // __fp16 ext_vector(2)
  union { decltype(r) h; unsigned u; } x;
  x.h = r;
  return x.u;
}

__device__ __forceinline__ f4 max4(f4 a, f4 b) {
  f4 r;
  r[0] = fmaxf(a[0], b[0]); r[1] = fmaxf(a[1], b[1]);
  r[2] = fmaxf(a[2], b[2]); r[3] = fmaxf(a[3], b[3]);
  return r;
}

// ---------------- QKV projection via compensated fp16 MFMA ----------------
// Internal W/X split keeps LOSCALE (W resid would be fp16-subnormal);
// OUTPUT residuals Ql/Kl are stored UNSCALED (fp16-normal range) so attn
// can accumulate compensation MFMAs directly into the main accumulator.
__global__ __launch_bounds__(256) void qkv_mfma(
    const float* __restrict__ x, const float* __restrict__ wqkv,
    _Float16* __restrict__ Qh, _Float16* __restrict__ Ql,
    _Float16* __restrict__ Kh, _Float16* __restrict__ Kl,
    _Float16* __restrict__ Vv) {
  __shared__ __align__(16) char QS[49152];
  char* Wh = QS;
  char* Wl = QS + 16384;
  char* Xh = QS + 32768;
  char* Xl = QS + 40960;

  const int tid = threadIdx.x;
  const int lane = tid & 63;
  const int w = tid >> 6;
  const int c = lane & 15;
  const int g = lane >> 4;
  const int o0 = blockIdx.x * 128;
  const int p0 = blockIdx.y * 64;
  const int b = blockIdx.z;

  // ---- stage W tile (hi/lo fp16, chunked+swizzled, b128 conflict-free) ----
  #pragma unroll
  for (int it = 0; it < 4; ++it) {
    int task = tid + it * 256;
    int oct = task & 7, o = task >> 3;
    const f4* wr = (const f4*)(wqkv + (size_t)(o0 + o) * CIN + oct * 8);
    f4 wa = wr[0], wb = wr[1];
    h8 hi, lo;
    #pragma unroll
    for (int e = 0; e < 8; ++e) {
      float v = e < 4 ? wa[e] : wb[e - 4];
      _Float16 h = (_Float16)v;
      hi[e] = h;
      lo[e] = (_Float16)((v - (float)h) * LOSCALE);
    }
    int byo = o * 128 + ((oct ^ (o & 7)) << 4);
    *(h8*)(Wh + byo) = hi;
    *(h8*)(Wl + byo) = lo;
  }
  // ---- stage X transposed via c-pair-packed u32 (conflict-free banks) ----
  {
    int kp = tid & 31;      // c-pair: channels 2kp, 2kp+1
    int pgrp = tid >> 5;    // p-octet 0..7
    const float* xr0 = x + ((size_t)b * CIN + 2 * kp) * NPIX + p0 + pgrp * 8;
    const float* xr1 = xr0 + NPIX;
    f4 a0 = *(const f4*)xr0, a1 = *(const f4*)(xr0 + 4);
    f4 b0 = *(const f4*)xr1, b1 = *(const f4*)(xr1 + 4);
    int oct = kp >> 2;
    int slot4 = (kp & 3) * 4;
    #pragma unroll
    for (int e = 0; e < 8; ++e) {
      float v0 = e < 4 ? a0[e] : a1[e - 4];
      float v1 = e < 4 ? b0[e] : b1[e - 4];
      _Float16 h0 = (_Float16)v0, h1 = (_Float16)v1;
      float l0f = (v0 - (float)h0) * LOSCALE;
      float l1f = (v1 - (float)h1) * LOSCALE;
      int p = pgrp * 8 + e;
      int byo = p * 128 + ((oct ^ (p & 7)) << 4) + slot4;
      union { h2 h; unsigned u; } uh, ul;
      uh.h[0] = h0; uh.h[1] = h1;
      ul.h[0] = (_Float16)l0f; ul.h[1] = (_Float16)l1f;
      *(unsigned*)(Xh + byo) = uh.u;
      *(unsigned*)(Xl + byo) = ul.u;
    }
  }
  __syncthreads();

  f4 zf = {0.f, 0.f, 0.f, 0.f};
  f4 acc[2][4], cor[2][4];
  #pragma unroll
  for (int oi = 0; oi < 2; ++oi)
    #pragma unroll
    for (int pi = 0; pi < 4; ++pi) { acc[oi][pi] = zf; cor[oi][pi] = zf; }

  const int ob = w * 32;
  #pragma unroll
  for (int kh = 0; kh < 2; ++kh) {
    h8 ah[2], al[2], bh[4], bl[4];
    #pragma unroll
    for (int oi = 0; oi < 2; ++oi) {
      int orow = ob + ((c >> 2) << 3) + (c & 3) + oi * 4;
      int ch = (((kh * 4 + g) ^ (orow & 7)) << 4);
      ah[oi] = *(const h8*)(Wh + orow * 128 + ch);
      al[oi] = *(const h8*)(Wl + orow * 128 + ch);
    }
    #pragma unroll
    for (int pi = 0; pi < 4; ++pi) {
      int prow = pi * 16 + c;
      int ch = (((kh * 4 + g) ^ (prow & 7)) << 4);
      bh[pi] = *(const h8*)(Xh + prow * 128 + ch);
      bl[pi] = *(const h8*)(Xl + prow * 128 + ch);
    }
    __builtin_amdgcn_s_setprio(1);
    #pragma unroll
    for (int oi = 0; oi < 2; ++oi)
      #pragma unroll
      for (int pi = 0; pi < 4; ++pi) {
        acc[oi][pi] = __builtin_amdgcn_mfma_f32_16x16x32_f16(ah[oi], bh[pi], acc[oi][pi], 0, 0, 0);
        cor[oi][pi] = __builtin_amdgcn_mfma_f32_16x16x32_f16(ah[oi], bl[pi], cor[oi][pi], 0, 0, 0);
        cor[oi][pi] = __builtin_amdgcn_mfma_f32_16x16x32_f16(al[oi], bh[pi], cor[oi][pi], 0, 0, 0);
      }
    __builtin_amdgcn_s_setprio(0);
  }

  const int part = o0 >> 9;
  const float scl = part == 0 ? QSCALE : 1.0f;
  _Float16* dsth = part == 0 ? Qh : (part == 1 ? Kh : Vv);
  _Float16* dstl = part == 0 ? Ql : (part == 1 ? Kl : nullptr);
  #pragma unroll
  for (int pi = 0; pi < 4; ++pi) {
    int obase = o0 + ob + 8 * g;
    int h = (obase >> 6) & 7;
    int d = obase & 63;
    int p_abs = p0 + pi * 16 + c;
    size_t off = (((size_t)(b * NH + h)) * NPIX + p_abs) * DH + d;
    h8 hv, lv;
    #pragma unroll
    for (int oi = 0; oi < 2; ++oi)
      #pragma unroll
      for (int reg = 0; reg < 4; ++reg) {
        float v = (acc[oi][pi][reg] + cor[oi][pi][reg] * INV_LOSCALE) * scl;
        _Float16 hh = (_Float16)v;
        hv[oi * 4 + reg] = hh;
        lv[oi * 4 + reg] = (_Float16)(v - (float)hh);   // UNSCALED residual
      }
    *(h8*)(dsth + off) = hv;
    if (dstl) *(h8*)(dstl + off) = lv;
  }
}

// ---------------- fused MFMA attention (swapped QK^T, lane-local rows) ----
// LDS (64KB): KH[2] 0..16K | KL[2] 16K..32K | VB[2] 32K..48K | SP 48K..56K
//             LHc 56K..64K ([16 t][128 rows][2] fp16).
__global__ __launch_bounds__(256, 2) void attn_mfma(
    const _Float16* __restrict__ Qh, const _Float16* __restrict__ Ql,
    const _Float16* __restrict__ Kh, const _Float16* __restrict__ Kl,
    const _Float16* __restrict__ V,
    const float* __restrict__ rel_h, const float* __restrict__ rel_w,
    float* __restrict__ out) {
  __shared__ __align__(16) char SMem[65536];
  char* SP = SMem + 49152;
  _Float16* LHc = (_Float16*)(SMem + 57344);  // [16 t][128 rows][2] fp16
  _Float16* LWT = (_Float16*)(SMem + 32768);  // prologue temp [128][64]
  float* OT = (float*)SMem;                   // epilogue [64][128] f32

  const int tid = threadIdx.x;
  const int lane = tid & 63;
  const int w = tid >> 6;
  const int wu = __builtin_amdgcn_readfirstlane(w);
  const int c = lane & 15;
  const int g = lane >> 4;
  const int bx = blockIdx.x;
  const int bh = ((bx & 7) << 3) | ((bx >> 3) & 7);
  const int i0 = (bx >> 6) << 7;
  const int swz = (c & 7) << 4;

  const _Float16* Qhg = Qh + (size_t)bh * NPIX * DH;
  const _Float16* Qlg = Ql + (size_t)bh * NPIX * DH;
  const _Float16* Khg = Kh + (size_t)bh * NPIX * DH;
  const _Float16* Klg = Kl + (size_t)bh * NPIX * DH;
  const _Float16* Vg  = V  + (size_t)bh * NPIX * DH;

  // Q fragments (used as B operand: B[col=c] = Q[i = base+c][d-octet])
  const h8* Qr0h = (const h8*)(Qhg + (size_t)(i0 + w * 32 + c) * DH);
  const h8* Qr0l = (const h8*)(Qlg + (size_t)(i0 + w * 32 + c) * DH);
  const h8* Qr1h = (const h8*)(Qhg + (size_t)(i0 + w * 32 + 16 + c) * DH);
  const h8* Qr1l = (const h8*)(Qlg + (size_t)(i0 + w * 32 + 16 + c) * DH);
  h8 q0h[2] = {Qr0h[g], Qr0h[4 + g]};
  h8 q0l[2] = {Qr0l[g], Qr0l[4 + g]};
  h8 q1h[2] = {Qr1h[g], Qr1h[4 + g]};
  h8 q1l[2] = {Qr1l[g], Qr1l[4 + g]};

  // K staging: pre-swizzled per-lane global byte offsets (linear LDS dest)
  const int s0i = wu * 128 + lane;
  const int s1i = s0i + 64;
  const int ko0 = (s0i >> 3) * 128 + (((s0i & 7) ^ ((s0i >> 3) & 7)) << 4);
  const int ko1 = (s1i >> 3) * 128 + (((s1i & 7) ^ ((s1i >> 3) & 7)) << 4);

  // ---- stage rel tables as fp16 chunks: rel_h -> KH0, rel_w -> KL0 ----
  #pragma unroll
  for (int it = 0; it < 2; ++it) {
    int task = tid + it * 256;
    int oct = task & 7, s = task >> 3;
    int ss = s < 63 ? s : 62;
    const float* sh = rel_h + (size_t)ss * DH + oct * 8;
    const float* sw = rel_w + (size_t)ss * DH + oct * 8;
    h8 hh, ww;
    #pragma unroll
    for (int e = 0; e < 8; ++e) {
      hh[e] = (_Float16)sh[e];
      ww[e] = (_Float16)sw[e];
    }
    int byo = s * 128 + ((oct ^ (s & 7)) << 4);
    *(h8*)(SMem + byo) = hh;
    *(h8*)(SMem + 16384 + byo) = ww;
  }
  __syncthreads();

  // ---- lh/lw tables via swapped MFMA (lo folded into same acc) ----
  const int yi = (i0 + w * 32) >> 5;   // same for both rowsets
  f4 zf = {0.f, 0.f, 0.f, 0.f};
  #pragma unroll
  for (int rs = 0; rs < 2; ++rs) {
    f4 lhD[4], lwD[4];
    #pragma unroll
    for (int st = 0; st < 4; ++st) { lhD[st] = zf; lwD[st] = zf; }
    #pragma unroll
    for (int kh = 0; kh < 2; ++kh) {
      h8 bq = rs ? q1h[kh] : q0h[kh];
      h8 bl = rs ? q1l[kh] : q0l[kh];
      #pragma unroll
      for (int st = 0; st < 4; ++st) {
        int srow = st * 16 + c;
        int chb = srow * 128 + (((kh * 4 + g) ^ (srow & 7)) << 4);
        h8 ra = *(const h8*)(SMem + chb);
        h8 wa = *(const h8*)(SMem + 16384 + chb);
        lhD[st] = __builtin_amdgcn_mfma_f32_16x16x32_f16(ra, bq, lhD[st], 0, 0, 0);
        lhD[st] = __builtin_amdgcn_mfma_f32_16x16x32_f16(ra, bl, lhD[st], 0, 0, 0);
        lwD[st] = __builtin_amdgcn_mfma_f32_16x16x32_f16(wa, bq, lwD[st], 0, 0, 0);
        lwD[st] = __builtin_amdgcn_mfma_f32_16x16x32_f16(wa, bl, lwD[st], 0, 0, 0);
      }
    }
    int lrow = w * 32 + rs * 16 + c;
    #pragma unroll
    for (int st = 0; st < 4; ++st)
      #pragma unroll
      for (int reg = 0; reg < 4; ++reg) {
        int s = st * 16 + 4 * g + reg;
        int k = s - 31 + yi;
        if (k >= 0 && k < 32)
          LHc[(k >> 1) * 256 + lrow * 2 + (k & 1)] = (_Float16)lhD[st][reg];
        LWT[lrow * 64 + s] = (_Float16)lwD[st][reg];
      }
  }
  __syncthreads();

  // lw registers: lwp[rs][jbp*4+reg] = lw[i][31 + jbp*16 + 4g+reg - xi]
  float lwp0[8], lwp1[8];
  #pragma unroll
  for (int jbp = 0; jbp < 2; ++jbp)
    #pragma unroll
    for (int reg = 0; reg < 4; ++reg) {
      lwp0[jbp * 4 + reg] = (float)LWT[(w * 32 + c) * 64 + 31 + jbp * 16 + 4 * g + reg - c];
      lwp1[jbp * 4 + reg] = (float)LWT[(w * 32 + 16 + c) * 64 + 31 + jbp * 16 + 4 * g + reg - 16 - c];
    }
  __syncthreads();

  // ---- stage tile 0 (K gloads -> buf0; V reg->LDS buf0) ----
  {
    gload_lds16((const char*)Khg + ko0, SMem + wu * 2048);
    gload_lds16((const char*)Khg + ko1, SMem + wu * 2048 + 1024);
    gload_lds16((const char*)Klg + ko0, SMem + 16384 + wu * 2048);
    gload_lds16((const char*)Klg + ko1, SMem + 16384 + wu * 2048 + 1024);
    int jp = tid & 31, dd = tid >> 5;
    const h8* vr = (const h8*)(Vg + (size_t)(2 * jp) * DH);
    h8 v0 = vr[dd], v1 = vr[8 + dd];
    us8 u0 = *(const us8*)&v0, u1 = *(const us8*)&v1;
    #pragma unroll
    for (int e = 0; e < 8; ++e) {
      int d = dd * 8 + e;
      unsigned int val = (unsigned int)u0[e] | ((unsigned int)u1[e] << 16);
      *(unsigned int*)(SMem + 32768 + d * 128 + (((jp >> 2) ^ (d & 7)) << 4) + (jp & 3) * 4) = val;
    }
  }
  __syncthreads();

  float m0 = -1e30f, m1 = -1e30f, lp0 = 0.f, lp1 = 0.f;
  f4 o0_[4], o1_[4];
  #pragma unroll
  for (int dt = 0; dt < 4; ++dt) { o0_[dt] = zf; o1_[dt] = zf; }

  int cur = 0;
  #pragma unroll 1
  for (int t = 0; t < 16; ++t) {
    char* Kc  = SMem + cur * 8192;
    char* KLc = SMem + 16384 + cur * 8192;
    char* Vc  = SMem + 32768 + cur * 8192;
    const int nxt = cur ^ 1;
    const bool pre = t < 15;
    const int jp = tid & 31, dd = tid >> 5;
    h8 v0 = {}, v1 = {};
    if (pre) {   // issue next-tile loads early (latency hides under QK)
      const char* kg  = (const char*)Khg + (size_t)(t + 1) * 8192;
      const char* klg = (const char*)Klg + (size_t)(t + 1) * 8192;
      gload_lds16(kg + ko0, SMem + nxt * 8192 + wu * 2048);
      gload_lds16(kg + ko1, SMem + nxt * 8192 + wu * 2048 + 1024);
      gload_lds16(klg + ko0, SMem + 16384 + nxt * 8192 + wu * 2048);
      gload_lds16(klg + ko1, SMem + 16384 + nxt * 8192 + wu * 2048 + 1024);
      const h8* vr = (const h8*)(Vg + (size_t)((t + 1) * 64 + 2 * jp) * DH);
      v0 = vr[dd];
      v1 = vr[8 + dd];
    }

    // ---- QK^T swapped, compensation folded into the same accumulator ----
    f4 s0[4], s1[4];
    #pragma unroll
    for (int jb = 0; jb < 4; ++jb) { s0[jb] = zf; s1[jb] = zf; }
    #pragma unroll
    for (int kh = 0; kh < 2; ++kh) {
      h8 b0h = q0h[kh], b0l = q0l[kh], b1h = q1h[kh], b1l = q1l[kh];
      #pragma unroll
      for (int jb = 0; jb < 4; ++jb) {
        int chb = (jb * 16 + c) * 128 + (((kh * 4 + g) ^ (c & 7)) << 4);
        h8 ah = *(const h8*)(Kc + chb);
        h8 al = *(const h8*)(KLc + chb);
        __builtin_amdgcn_s_setprio(1);
        s0[jb] = __builtin_amdgcn_mfma_f32_16x16x32_f16(ah, b0h, s0[jb], 0, 0, 0);
        s0[jb] = __builtin_amdgcn_mfma_f32_16x16x32_f16(al, b0h, s0[jb], 0, 0, 0);
        s0[jb] = __builtin_amdgcn_mfma_f32_16x16x32_f16(ah, b0l, s0[jb], 0, 0, 0);
        s1[jb] = __builtin_amdgcn_mfma_f32_16x16x32_f16(ah, b1h, s1[jb], 0, 0, 0);
        s1[jb] = __builtin_amdgcn_mfma_f32_16x16x32_f16(al, b1h, s1[jb], 0, 0, 0);
        s1[jb] = __builtin_amdgcn_mfma_f32_16x16x32_f16(ah, b1l, s1[jb], 0, 0, 0);
        __builtin_amdgcn_s_setprio(0);
      }
    }

    // finish: bias + online softmax (scalar state) + packed b64 P write
    auto finish = [&](f4* s_, const float* lwp, float& m_s, float& lp,
                      f4* o_, int rs) {
      int rr = w * 32 + rs * 16 + c;
      h2 lhu = *(const h2*)(LHc + t * 256 + rr * 2);
      float lh0 = (float)lhu[0], lh1 = (float)lhu[1];
      #pragma unroll
      for (int jb = 0; jb < 4; ++jb) {
        float lhv = (jb >> 1) ? lh1 : lh0;
        #pragma unroll
        for (int reg = 0; reg < 4; ++reg)
          s_[jb][reg] += lwp[(jb & 1) * 4 + reg] + lhv;
      }
      f4 ef = max4(max4(s_[0], s_[1]), max4(s_[2], s_[3]));
      float mx = fmaxf(fmaxf(ef[0], ef[1]), fmaxf(ef[2], ef[3]));
      mx = fmaxf(mx, __shfl_xor(mx, 16, 64));
      mx = fmaxf(mx, __shfl_xor(mx, 32, 64));
      bool sk = mx <= m_s + DTHR;      // T13 defer-max
      if (!__all(sk)) {
        float mn = fmaxf(m_s, mx);
        float corr = fexp2(m_s - mn);
        m_s = mn;
        lp *= corr;
        #pragma unroll
        for (int dt = 0; dt < 4; ++dt)
          #pragma unroll
          for (int reg = 0; reg < 4; ++reg)
            o_[dt][reg] *= corr;
      }
      f4 psum = zf;
      char* pbse = SP + w * 2048 + c * 128;
      #pragma unroll
      for (int jb = 0; jb < 4; ++jb) {
        f4 p;
        #pragma unroll
        for (int reg = 0; reg < 4; ++reg) p[reg] = fexp2(s_[jb][reg] - m_s);
        psum[0] += p[0]; psum[1] += p[1]; psum[2] += p[2]; psum[3] += p[3];
        unsigned long long u = (unsigned long long)pk16(p[0], p[1]) |
                               ((unsigned long long)pk16(p[2], p[3]) << 32);
        *(unsigned long long*)(pbse + ((jb * 32 + 8 * g) ^ swz)) = u;
      }
      lp += (psum[0] + psum[1]) + (psum[2] + psum[3]);
    };

    finish(s0, lwp0, m0, lp0, o0_, 0);
    __builtin_amdgcn_wave_barrier();

    // ---- PV rowset0 (swapped: A=V, B=P), cache V fragments; finish1's
    //      VALU co-schedules with these MFMAs ----
    h8 vbr[2][4];
    #pragma unroll
    for (int kh = 0; kh < 2; ++kh) {
      int och = ((kh * 4 + g) ^ (c & 7)) << 4;
      h8 pb = *(const h8*)(SP + w * 2048 + c * 128 + och);
      __builtin_amdgcn_s_setprio(1);
      #pragma unroll
      for (int dt = 0; dt < 4; ++dt) {
        vbr[kh][dt] = *(const h8*)(Vc + (dt * 16 + c) * 128 + och);
        o0_[dt] = __builtin_amdgcn_mfma_f32_16x16x32_f16(vbr[kh][dt], pb, o0_[dt], 0, 0, 0);
      }
      __builtin_amdgcn_s_setprio(0);
    }

    finish(s1, lwp1, m1, lp1, o1_, 1);
    __builtin_amdgcn_wave_barrier();

    // ---- PV rowset1 (reuse V fragments) ----
    #pragma unroll
    for (int kh = 0; kh < 2; ++kh) {
      int och = ((kh * 4 + g) ^ (c & 7)) << 4;
      h8 pb = *(const h8*)(SP + w * 2048 + c * 128 + och);
      __builtin_amdgcn_s_setprio(1);
      #pragma unroll
      for (int dt = 0; dt < 4; ++dt)
        o1_[dt] = __builtin_amdgcn_mfma_f32_16x16x32_f16(vbr[kh][dt], pb, o1_[dt], 0, 0, 0);
      __builtin_amdgcn_s_setprio(0);
    }

    if (pre) {   // T14: write prefetched V after compute
      us8 u0 = *(const us8*)&v0, u1 = *(const us8*)&v1;
      char* Vn = SMem + 32768 + nxt * 8192;
      #pragma unroll
      for (int e = 0; e < 8; ++e) {
        int d = dd * 8 + e;
        unsigned int val = (unsigned int)u0[e] | ((unsigned int)u1[e] << 16);
        *(unsigned int*)(Vn + d * 128 + (((jp >> 2) ^ (d & 7)) << 4) + (jp & 3) * 4) = val;
      }
    }
    __syncthreads();
    cur = nxt;
  }

  // ---- epilogue: reduce l across g, normalize, transpose via OT, store ----
  float a0 = lp0;
  a0 += __shfl_xor(a0, 16, 64);
  a0 += __shfl_xor(a0, 32, 64);
  float r0 = __builtin_amdgcn_rcpf(a0);
  float a1 = lp1;
  a1 += __shfl_xor(a1, 16, 64);
  a1 += __shfl_xor(a1, 32, 64);
  float r1 = __builtin_amdgcn_rcpf(a1);
  #pragma unroll
  for (int dt = 0; dt < 4; ++dt)
    #pragma unroll
    for (int reg = 0; reg < 4; ++reg) {
      int d = dt * 16 + 4 * g + reg;
      int sw = (d & 7) << 3;
      int il0 = w * 32 + c;
      OT[d * 128 + (il0 ^ sw)] = o0_[dt][reg] * r0;
      OT[d * 128 + ((il0 + 16) ^ sw)] = o1_[dt][reg] * r1;
    }
  __syncthreads();
  #pragma unroll
  for (int it = 0; it < 8; ++it) {
    int task = tid + it * 256;
    int rq = task & 31, d = task >> 5;
    f4 vv = *(const f4*)&OT[d * 128 + ((rq * 4) ^ ((d & 7) << 3))];
    *(f4*)(out + (((size_t)bh * 64 + d) << 10) + i0 + rq * 4) = vv;
  }
}

extern "C" void kernel_launch(void* const* d_in, const int* in_sizes, int n_in,
                              void* d_out, int out_size, void* d_ws, size_t ws_size,
                              hipStream_t stream) {
  const float* x  = (const float*)d_in[0];
  const float* wq = (const float*)d_in[1];
  const float* rh = (const float*)d_in[2];
  const float* rw = (const float*)d_in[3];
  float* out = (float*)d_out;

  const size_t sz = (size_t)NBH * NPIX * DH;
  _Float16* Qh = (_Float16*)d_ws;
  _Float16* Ql = Qh + sz;
  _Float16* Kh = Ql + sz;
  _Float16* Kl = Kh + sz;
  _Float16* V  = Kl + sz;

  qkv_mfma<<<dim3(12, 16, 8), 256, 0, stream>>>(x, wq, Qh, Ql, Kh, Kl, V);
  attn_mfma<<<dim3(512), 256, 0, stream>>>(Qh, Ql, Kh, Kl, V, rh, rw, out);
}

// Round 12
// 76.013 us; speedup vs baseline: 2.7758x; 1.0373x over previous
//
#include <hip/hip_runtime.h>
#include <hip/hip_bf16.h>
#include <hip/hip_fp16.h>

typedef _Float16 h8 __attribute__((ext_vector_type(8)));
typedef _Float16 h2 __attribute__((ext_vector_type(2)));
typedef unsigned short us8 __attribute__((ext_vector_type(8)));
typedef float f4 __attribute__((ext_vector_type(4)));
typedef float f16v __attribute__((ext_vector_type(16)));

#define NH 8
#define DH 64
#define NPIX 1024
#define CIN 64
#define NBH 64
// 512 (ref scale) * log2(e): logits come out in base-2 units
#define QSCALE (512.0f * 1.44269504f)
#define LOSCALE 2048.0f
#define INV_LOSCALE (1.0f / 2048.0f)
#define DTHR 12.0f

__device__ __forceinline__ void gload_lds16(const void* g, void* lds) {
  __builtin_amdgcn_global_load_lds(
      (const __attribute__((address_space(1))) void*)g,
      (__attribute__((address_space(3))) void*)lds, 16, 0, 0);
}

__device__ __forceinline__ float fexp2(float x) {
#if __has_builtin(__builtin_amdgcn_exp2f)
  return __builtin_amdgcn_exp2f(x);
#else
  return exp2f(x);
#endif
}

__device__ __forceinline__ unsigned pk16(float a, float b) {
  auto r = __builtin_amdgcn_cvt_pkrtz(a, b);   // __fp16 ext_vector(2)
  union { decltype(r) h; unsigned u; } x;
  x.h = r;
  return x.u;
}

// ---------------- QKV projection via compensated fp16 MFMA ----------------
__global__ __launch_bounds__(256) void qkv_mfma(
    const float* __restrict__ x, const float* __restrict__ wqkv,
    _Float16* __restrict__ Qh, _Float16* __restrict__ Ql,
    _Float16* __restrict__ Kh, _Float16* __restrict__ Kl,
    _Float16* __restrict__ Vv) {
  __shared__ __align__(16) char QS[49152];
  char* Wh = QS;
  char* Wl = QS + 16384;
  char* Xh = QS + 32768;
  char* Xl = QS + 40960;

  const int tid = threadIdx.x;
  const int lane = tid & 63;
  const int w = tid >> 6;
  const int c = lane & 15;
  const int g = lane >> 4;
  const int o0 = blockIdx.x * 128;
  const int p0 = blockIdx.y * 64;
  const int b = blockIdx.z;

  #pragma unroll
  for (int it = 0; it < 4; ++it) {
    int task = tid + it * 256;
    int oct = task & 7, o = task >> 3;
    const f4* wr = (const f4*)(wqkv + (size_t)(o0 + o) * CIN + oct * 8);
    f4 wa = wr[0], wb = wr[1];
    h8 hi, lo;
    #pragma unroll
    for (int e = 0; e < 8; ++e) {
      float v = e < 4 ? wa[e] : wb[e - 4];
      _Float16 h = (_Float16)v;
      hi[e] = h;
      lo[e] = (_Float16)((v - (float)h) * LOSCALE);
    }
    int byo = o * 128 + ((oct ^ (o & 7)) << 4);
    *(h8*)(Wh + byo) = hi;
    *(h8*)(Wl + byo) = lo;
  }
  {
    int kp = tid & 31;      // c-pair: channels 2kp, 2kp+1
    int pgrp = tid >> 5;    // p-octet 0..7
    const float* xr0 = x + ((size_t)b * CIN + 2 * kp) * NPIX + p0 + pgrp * 8;
    const float* xr1 = xr0 + NPIX;
    f4 a0 = *(const f4*)xr0, a1 = *(const f4*)(xr0 + 4);
    f4 b0 = *(const f4*)xr1, b1 = *(const f4*)(xr1 + 4);
    int oct = kp >> 2;
    int slot4 = (kp & 3) * 4;
    #pragma unroll
    for (int e = 0; e < 8; ++e) {
      float v0 = e < 4 ? a0[e] : a1[e - 4];
      float v1 = e < 4 ? b0[e] : b1[e - 4];
      _Float16 h0 = (_Float16)v0, h1 = (_Float16)v1;
      float l0f = (v0 - (float)h0) * LOSCALE;
      float l1f = (v1 - (float)h1) * LOSCALE;
      int p = pgrp * 8 + e;
      int byo = p * 128 + ((oct ^ (p & 7)) << 4) + slot4;
      union { h2 h; unsigned u; } uh, ul;
      uh.h[0] = h0; uh.h[1] = h1;
      ul.h[0] = (_Float16)l0f; ul.h[1] = (_Float16)l1f;
      *(unsigned*)(Xh + byo) = uh.u;
      *(unsigned*)(Xl + byo) = ul.u;
    }
  }
  __syncthreads();

  f4 zf = {0.f, 0.f, 0.f, 0.f};
  f4 acc[2][4], cor[2][4];
  #pragma unroll
  for (int oi = 0; oi < 2; ++oi)
    #pragma unroll
    for (int pi = 0; pi < 4; ++pi) { acc[oi][pi] = zf; cor[oi][pi] = zf; }

  const int ob = w * 32;
  #pragma unroll
  for (int kh = 0; kh < 2; ++kh) {
    h8 ah[2], al[2], bh[4], bl[4];
    #pragma unroll
    for (int oi = 0; oi < 2; ++oi) {
      int orow = ob + ((c >> 2) << 3) + (c & 3) + oi * 4;
      int ch = (((kh * 4 + g) ^ (orow & 7)) << 4);
      ah[oi] = *(const h8*)(Wh + orow * 128 + ch);
      al[oi] = *(const h8*)(Wl + orow * 128 + ch);
    }
    #pragma unroll
    for (int pi = 0; pi < 4; ++pi) {
      int prow = pi * 16 + c;
      int ch = (((kh * 4 + g) ^ (prow & 7)) << 4);
      bh[pi] = *(const h8*)(Xh + prow * 128 + ch);
      bl[pi] = *(const h8*)(Xl + prow * 128 + ch);
    }
    __builtin_amdgcn_s_setprio(1);
    #pragma unroll
    for (int oi = 0; oi < 2; ++oi)
      #pragma unroll
      for (int pi = 0; pi < 4; ++pi) {
        acc[oi][pi] = __builtin_amdgcn_mfma_f32_16x16x32_f16(ah[oi], bh[pi], acc[oi][pi], 0, 0, 0);
        cor[oi][pi] = __builtin_amdgcn_mfma_f32_16x16x32_f16(ah[oi], bl[pi], cor[oi][pi], 0, 0, 0);
        cor[oi][pi] = __builtin_amdgcn_mfma_f32_16x16x32_f16(al[oi], bh[pi], cor[oi][pi], 0, 0, 0);
      }
    __builtin_amdgcn_s_setprio(0);
  }

  const int part = o0 >> 9;
  const float scl = part == 0 ? QSCALE : 1.0f;
  _Float16* dsth = part == 0 ? Qh : (part == 1 ? Kh : Vv);
  _Float16* dstl = part == 0 ? Ql : (part == 1 ? Kl : nullptr);
  #pragma unroll
  for (int pi = 0; pi < 4; ++pi) {
    int obase = o0 + ob + 8 * g;
    int h = (obase >> 6) & 7;
    int d = obase & 63;
    int p_abs = p0 + pi * 16 + c;
    size_t off = (((size_t)(b * NH + h)) * NPIX + p_abs) * DH + d;
    h8 hv, lv;
    #pragma unroll
    for (int oi = 0; oi < 2; ++oi)
      #pragma unroll
      for (int reg = 0; reg < 4; ++reg) {
        float v = (acc[oi][pi][reg] + cor[oi][pi][reg] * INV_LOSCALE) * scl;
        _Float16 hh = (_Float16)v;
        hv[oi * 4 + reg] = hh;
        lv[oi * 4 + reg] = (_Float16)(v - (float)hh);   // UNSCALED residual
      }
    *(h8*)(dsth + off) = hv;
    if (dstl) *(h8*)(dstl + off) = lv;
  }
}

// ---------------- fused MFMA attention: 32x32x16, one finish per tile ----
// Wave w owns rows i = w*32 + (lane&31); k/j slot = lane>>5.
// LDS (72KB): KH[2] 0..16K | KL[2] 16K..32K | VB[2] 32K..48K |
//             SP 48K..64K (4KB/wave) | LHc 64K..72K ([16 t][128 rows][2]).
__global__ __launch_bounds__(256, 2) void attn_mfma(
    const _Float16* __restrict__ Qh, const _Float16* __restrict__ Ql,
    const _Float16* __restrict__ Kh, const _Float16* __restrict__ Kl,
    const _Float16* __restrict__ V,
    const float* __restrict__ rel_h, const float* __restrict__ rel_w,
    float* __restrict__ out) {
  __shared__ __align__(16) char SMem[73728];
  _Float16* LHc = (_Float16*)(SMem + 65536);  // [16 t][128 rows][2] fp16
  _Float16* LWT = (_Float16*)(SMem + 32768);  // prologue temp [128][64]
  float* OT = (float*)SMem;                   // epilogue [64][128] f32

  const int tid = threadIdx.x;
  const int lane = tid & 63;
  const int w = tid >> 6;
  const int wu = __builtin_amdgcn_readfirstlane(w);
  const int c = lane & 15;
  const int g = lane >> 4;
  const int il = lane & 31;
  const int hi = lane >> 5;
  const int bx = blockIdx.x;
  const int bh = ((bx & 7) << 3) | ((bx >> 3) & 7);
  const int i0 = (bx >> 6) << 7;
  char* SPw = SMem + 49152 + w * 4096;

  const _Float16* Qhg = Qh + (size_t)bh * NPIX * DH;
  const _Float16* Qlg = Ql + (size_t)bh * NPIX * DH;
  const _Float16* Khg = Kh + (size_t)bh * NPIX * DH;
  const _Float16* Klg = Kl + (size_t)bh * NPIX * DH;
  const _Float16* Vg  = V  + (size_t)bh * NPIX * DH;

  // prologue Q fragments (16x16 B operand), reused layout from r11
  const h8* Qr0h = (const h8*)(Qhg + (size_t)(i0 + w * 32 + c) * DH);
  const h8* Qr0l = (const h8*)(Qlg + (size_t)(i0 + w * 32 + c) * DH);
  const h8* Qr1h = (const h8*)(Qhg + (size_t)(i0 + w * 32 + 16 + c) * DH);
  const h8* Qr1l = (const h8*)(Qlg + (size_t)(i0 + w * 32 + 16 + c) * DH);
  h8 q0h[2] = {Qr0h[g], Qr0h[4 + g]};
  h8 q0l[2] = {Qr0l[g], Qr0l[4 + g]};
  h8 q1h[2] = {Qr1h[g], Qr1h[4 + g]};
  h8 q1l[2] = {Qr1l[g], Qr1l[4 + g]};

  // K staging offsets (pre-swizzled global source, linear LDS dest)
  const int s0i = wu * 128 + lane;
  const int s1i = s0i + 64;
  const int ko0 = (s0i >> 3) * 128 + (((s0i & 7) ^ ((s0i >> 3) & 7)) << 4);
  const int ko1 = (s1i >> 3) * 128 + (((s1i & 7) ^ ((s1i >> 3) & 7)) << 4);

  // ---- stage rel tables: rel_h -> KH0, rel_w -> KL0 ----
  #pragma unroll
  for (int it = 0; it < 2; ++it) {
    int task = tid + it * 256;
    int oct = task & 7, s = task >> 3;
    int ss = s < 63 ? s : 62;
    const float* sh = rel_h + (size_t)ss * DH + oct * 8;
    const float* sw = rel_w + (size_t)ss * DH + oct * 8;
    h8 hh, ww;
    #pragma unroll
    for (int e = 0; e < 8; ++e) {
      hh[e] = (_Float16)sh[e];
      ww[e] = (_Float16)sw[e];
    }
    int byo = s * 128 + ((oct ^ (s & 7)) << 4);
    *(h8*)(SMem + byo) = hh;
    *(h8*)(SMem + 16384 + byo) = ww;
  }
  __syncthreads();

  // ---- lh/lw tables via swapped 16x16 MFMA (lo folded into same acc) ----
  const int yi = (i0 + w * 32) >> 5;
  f4 zf = {0.f, 0.f, 0.f, 0.f};
  #pragma unroll
  for (int rs = 0; rs < 2; ++rs) {
    f4 lhD[4], lwD[4];
    #pragma unroll
    for (int st = 0; st < 4; ++st) { lhD[st] = zf; lwD[st] = zf; }
    #pragma unroll
    for (int kh = 0; kh < 2; ++kh) {
      h8 bq = rs ? q1h[kh] : q0h[kh];
      h8 bl = rs ? q1l[kh] : q0l[kh];
      #pragma unroll
      for (int st = 0; st < 4; ++st) {
        int srow = st * 16 + c;
        int chb = srow * 128 + (((kh * 4 + g) ^ (srow & 7)) << 4);
        h8 ra = *(const h8*)(SMem + chb);
        h8 wa = *(const h8*)(SMem + 16384 + chb);
        lhD[st] = __builtin_amdgcn_mfma_f32_16x16x32_f16(ra, bq, lhD[st], 0, 0, 0);
        lhD[st] = __builtin_amdgcn_mfma_f32_16x16x32_f16(ra, bl, lhD[st], 0, 0, 0);
        lwD[st] = __builtin_amdgcn_mfma_f32_16x16x32_f16(wa, bq, lwD[st], 0, 0, 0);
        lwD[st] = __builtin_amdgcn_mfma_f32_16x16x32_f16(wa, bl, lwD[st], 0, 0, 0);
      }
    }
    int lrow = w * 32 + rs * 16 + c;
    #pragma unroll
    for (int st = 0; st < 4; ++st)
      #pragma unroll
      for (int reg = 0; reg < 4; ++reg) {
        int s = st * 16 + 4 * g + reg;
        int k = s - 31 + yi;
        if (k >= 0 && k < 32)
          LHc[(k >> 1) * 256 + lrow * 2 + (k & 1)] = (_Float16)lhD[st][reg];
        LWT[lrow * 64 + s] = (_Float16)lwD[st][reg];
      }
  }
  __syncthreads();

  // lwp[reg]: lw[i][31 + jl(reg) - il], jl = (reg&3)+8*(reg>>2)+4*hi
  float lwp[16];
  {
    int r = w * 32 + il;
    #pragma unroll
    for (int reg = 0; reg < 16; ++reg) {
      int jl = (reg & 3) + 8 * (reg >> 2) + 4 * hi;
      lwp[reg] = (float)LWT[r * 64 + 31 + jl - il];
    }
  }
  // main-loop Q fragments (32x32 B operand: col = il, k-slot = hi)
  const h8* Qmh = (const h8*)(Qhg + (size_t)(i0 + w * 32 + il) * DH);
  const h8* Qml = (const h8*)(Qlg + (size_t)(i0 + w * 32 + il) * DH);
  h8 qmh[4], qml[4];
  #pragma unroll
  for (int kb = 0; kb < 4; ++kb) {
    qmh[kb] = Qmh[2 * kb + hi];
    qml[kb] = Qml[2 * kb + hi];
  }
  __syncthreads();

  // ---- stage tile 0 ----
  {
    gload_lds16((const char*)Khg + ko0, SMem + wu * 2048);
    gload_lds16((const char*)Khg + ko1, SMem + wu * 2048 + 1024);
    gload_lds16((const char*)Klg + ko0, SMem + 16384 + wu * 2048);
    gload_lds16((const char*)Klg + ko1, SMem + 16384 + wu * 2048 + 1024);
    int jp = tid & 31, dd = tid >> 5;
    const h8* vr = (const h8*)(Vg + (size_t)(2 * jp) * DH);
    h8 v0 = vr[dd], v1 = vr[8 + dd];
    us8 u0 = *(const us8*)&v0, u1 = *(const us8*)&v1;
    #pragma unroll
    for (int e = 0; e < 8; ++e) {
      int d = dd * 8 + e;
      unsigned int val = (unsigned int)u0[e] | ((unsigned int)u1[e] << 16);
      *(unsigned int*)(SMem + 32768 + d * 128 + (((jp >> 2) ^ (d & 7)) << 4) + (jp & 3) * 4) = val;
    }
  }
  __syncthreads();

  float m_s = -1e30f, lp = 0.f;
  f16v O0 = {0.f}, O1 = {0.f};
  #pragma unroll
  for (int e = 0; e < 16; ++e) { O0[e] = 0.f; O1[e] = 0.f; }

  const int swl = (il & 7);
  int cur = 0;
  #pragma unroll 1
  for (int t = 0; t < 16; ++t) {
    char* Kc  = SMem + cur * 8192;
    char* KLc = SMem + 16384 + cur * 8192;
    char* Vc  = SMem + 32768 + cur * 8192;
    const int nxt = cur ^ 1;
    const bool pre = t < 15;
    const int jp = tid & 31, dd = tid >> 5;
    h8 v0 = {}, v1 = {};
    if (pre) {
      const char* kg  = (const char*)Khg + (size_t)(t + 1) * 8192;
      const char* klg = (const char*)Klg + (size_t)(t + 1) * 8192;
      gload_lds16(kg + ko0, SMem + nxt * 8192 + wu * 2048);
      gload_lds16(kg + ko1, SMem + nxt * 8192 + wu * 2048 + 1024);
      gload_lds16(klg + ko0, SMem + 16384 + nxt * 8192 + wu * 2048);
      gload_lds16(klg + ko1, SMem + 16384 + nxt * 8192 + wu * 2048 + 1024);
      const h8* vr = (const h8*)(Vg + (size_t)((t + 1) * 64 + 2 * jp) * DH);
      v0 = vr[dd];
      v1 = vr[8 + dd];
    }

    // ---- QK^T swapped 32x32x16: S[jb] rows j, col i = il ----
    f16v S0 = O0 * 0.f, S1 = O0 * 0.f;
    #pragma unroll
    for (int e = 0; e < 16; ++e) { S0[e] = 0.f; S1[e] = 0.f; }
    #pragma unroll
    for (int kb = 0; kb < 4; ++kb) {
      int chb0 = il * 128 + (((2 * kb + hi) ^ swl) << 4);
      int chb1 = chb0 + 32 * 128;
      h8 a0h = *(const h8*)(Kc + chb0);
      h8 a0l = *(const h8*)(KLc + chb0);
      h8 a1h = *(const h8*)(Kc + chb1);
      h8 a1l = *(const h8*)(KLc + chb1);
      __builtin_amdgcn_s_setprio(1);
      S0 = __builtin_amdgcn_mfma_f32_32x32x16_f16(a0h, qmh[kb], S0, 0, 0, 0);
      S0 = __builtin_amdgcn_mfma_f32_32x32x16_f16(a0l, qmh[kb], S0, 0, 0, 0);
      S0 = __builtin_amdgcn_mfma_f32_32x32x16_f16(a0h, qml[kb], S0, 0, 0, 0);
      S1 = __builtin_amdgcn_mfma_f32_32x32x16_f16(a1h, qmh[kb], S1, 0, 0, 0);
      S1 = __builtin_amdgcn_mfma_f32_32x32x16_f16(a1l, qmh[kb], S1, 0, 0, 0);
      S1 = __builtin_amdgcn_mfma_f32_32x32x16_f16(a1h, qml[kb], S1, 0, 0, 0);
      __builtin_amdgcn_s_setprio(0);
    }

    // ---- finish (ONE per tile): bias + online softmax + packed P write ----
    {
      int r = w * 32 + il;
      h2 lhu = *(const h2*)(LHc + t * 256 + r * 2);
      float lh0 = (float)lhu[0], lh1 = (float)lhu[1];
      #pragma unroll
      for (int reg = 0; reg < 16; ++reg) {
        S0[reg] += lwp[reg] + lh0;
        S1[reg] += lwp[reg] + lh1;
      }
      float v8[8];
      #pragma unroll
      for (int e = 0; e < 8; ++e)
        v8[e] = fmaxf(fmaxf(S0[e], S0[e + 8]), fmaxf(S1[e], S1[e + 8]));
      float w0 = fmaxf(fmaxf(v8[0], v8[1]), fmaxf(v8[2], v8[3]));
      float w1 = fmaxf(fmaxf(v8[4], v8[5]), fmaxf(v8[6], v8[7]));
      float mx = fmaxf(w0, w1);
      mx = fmaxf(mx, __shfl_xor(mx, 32, 64));
      bool sk = mx <= m_s + DTHR;      // T13 defer-max
      if (!__all(sk)) {
        float mn = fmaxf(m_s, mx);
        float corr = fexp2(m_s - mn);
        m_s = mn;
        lp *= corr;
        #pragma unroll
        for (int e = 0; e < 16; ++e) { O0[e] *= corr; O1[e] *= corr; }
      }
      float sum = 0.f;
      char* pbse = SPw + il * 128 + hi * 8;
      #pragma unroll
      for (int a = 0; a < 4; ++a) {
        float p0 = fexp2(S0[4 * a + 0] - m_s);
        float p1 = fexp2(S0[4 * a + 1] - m_s);
        float p2 = fexp2(S0[4 * a + 2] - m_s);
        float p3 = fexp2(S0[4 * a + 3] - m_s);
        sum += (p0 + p1) + (p2 + p3);
        *(unsigned long long*)(pbse + ((a ^ swl) << 4)) =
            (unsigned long long)pk16(p0, p1) | ((unsigned long long)pk16(p2, p3) << 32);
      }
      #pragma unroll
      for (int a = 0; a < 4; ++a) {
        float p0 = fexp2(S1[4 * a + 0] - m_s);
        float p1 = fexp2(S1[4 * a + 1] - m_s);
        float p2 = fexp2(S1[4 * a + 2] - m_s);
        float p3 = fexp2(S1[4 * a + 3] - m_s);
        sum += (p0 + p1) + (p2 + p3);
        *(unsigned long long*)(pbse + (((4 + a) ^ swl) << 4)) =
            (unsigned long long)pk16(p0, p1) | ((unsigned long long)pk16(p2, p3) << 32);
      }
      lp += sum;
    }
    __builtin_amdgcn_wave_barrier();

    // ---- PV swapped 32x32x16: A=V, B=P ----
    #pragma unroll
    for (int jkb = 0; jkb < 4; ++jkb) {
      int ci = 2 * jkb + hi;
      int och = ((ci ^ swl) << 4);
      h8 pb = *(const h8*)(SPw + il * 128 + och);
      __builtin_amdgcn_s_setprio(1);
      h8 av0 = *(const h8*)(Vc + il * 128 + och);
      h8 av1 = *(const h8*)(Vc + (32 + il) * 128 + och);
      O0 = __builtin_amdgcn_mfma_f32_32x32x16_f16(av0, pb, O0, 0, 0, 0);
      O1 = __builtin_amdgcn_mfma_f32_32x32x16_f16(av1, pb, O1, 0, 0, 0);
      __builtin_amdgcn_s_setprio(0);
    }

    if (pre) {   // T14: write prefetched V after compute
      us8 u0 = *(const us8*)&v0, u1 = *(const us8*)&v1;
      char* Vn = SMem + 32768 + nxt * 8192;
      #pragma unroll
      for (int e = 0; e < 8; ++e) {
        int d = dd * 8 + e;
        unsigned int val = (unsigned int)u0[e] | ((unsigned int)u1[e] << 16);
        *(unsigned int*)(Vn + d * 128 + (((jp >> 2) ^ (d & 7)) << 4) + (jp & 3) * 4) = val;
      }
    }
    __syncthreads();
    cur = nxt;
  }

  // ---- epilogue: reduce l across hi, normalize, transpose, store ----
  float lt = lp + __shfl_xor(lp, 32, 64);
  float rr = __builtin_amdgcn_rcpf(lt);
  {
    int r = w * 32 + il;
    #pragma unroll
    for (int reg = 0; reg < 16; ++reg) {
      int dl = (reg & 3) + 8 * (reg >> 2) + 4 * hi;
      int d0 = dl;
      int d1 = 32 + dl;
      OT[d0 * 128 + (r ^ ((d0 & 7) << 3))] = O0[reg] * rr;
      OT[d1 * 128 + (r ^ ((d1 & 7) << 3))] = O1[reg] * rr;
    }
  }
  __syncthreads();
  #pragma unroll
  for (int it = 0; it < 8; ++it) {
    int task = tid + it * 256;
    int rq = task & 31, d = task >> 5;
    f4 vv = *(const f4*)&OT[d * 128 + ((rq * 4) ^ ((d & 7) << 3))];
    *(f4*)(out + (((size_t)bh * 64 + d) << 10) + i0 + rq * 4) = vv;
  }
}

extern "C" void kernel_launch(void* const* d_in, const int* in_sizes, int n_in,
                              void* d_out, int out_size, void* d_ws, size_t ws_size,
                              hipStream_t stream) {
  const float* x  = (const float*)d_in[0];
  const float* wq = (const float*)d_in[1];
  const float* rh = (const float*)d_in[2];
  const float* rw = (const float*)d_in[3];
  float* out = (float*)d_out;

  const size_t sz = (size_t)NBH * NPIX * DH;
  _Float16* Qh = (_Float16*)d_ws;
  _Float16* Ql = Qh + sz;
  _Float16* Kh = Ql + sz;
  _Float16* Kl = Kh + sz;
  _Float16* V  = Kl + sz;

  qkv_mfma<<<dim3(12, 16, 8), 256, 0, stream>>>(x, wq, Qh, Ql, Kh, Kl, V);
  attn_mfma<<<dim3(512), 256, 0, stream>>>(Qh, Ql, Kh, Kl, V, rh, rw, out);
}

// Round 13
// 72.101 us; speedup vs baseline: 2.9264x; 1.0543x over previous
//
#include <hip/hip_runtime.h>
#include <hip/hip_bf16.h>
#include <hip/hip_fp16.h>

typedef _Float16 h8 __attribute__((ext_vector_type(8)));
typedef _Float16 h2 __attribute__((ext_vector_type(2)));
typedef unsigned short us8 __attribute__((ext_vector_type(8)));
typedef float f4 __attribute__((ext_vector_type(4)));
typedef float f16v __attribute__((ext_vector_type(16)));
typedef int i2v __attribute__((ext_vector_type(2)));

#define NH 8
#define DH 64
#define NPIX 1024
#define CIN 64
#define NBH 64
// 512 (ref scale) * log2(e): logits come out in base-2 units
#define QSCALE (512.0f * 1.44269504f)
#define LOSCALE 2048.0f
#define INV_LOSCALE (1.0f / 2048.0f)
#define DTHR 12.0f

__device__ __forceinline__ void gload_lds16(const void* g, void* lds) {
  __builtin_amdgcn_global_load_lds(
      (const __attribute__((address_space(1))) void*)g,
      (__attribute__((address_space(3))) void*)lds, 16, 0, 0);
}

__device__ __forceinline__ float fexp2(float x) {
#if __has_builtin(__builtin_amdgcn_exp2f)
  return __builtin_amdgcn_exp2f(x);
#else
  return exp2f(x);
#endif
}

__device__ __forceinline__ unsigned pk16(float a, float b) {
  auto r = __builtin_amdgcn_cvt_pkrtz(a, b);   // __fp16 ext_vector(2)
  union { decltype(r) h; unsigned u; } x;
  x.h = r;
  return x.u;
}

// ---------------- QKV projection via compensated fp16 MFMA ----------------
__global__ __launch_bounds__(256) void qkv_mfma(
    const float* __restrict__ x, const float* __restrict__ wqkv,
    _Float16* __restrict__ Qh, _Float16* __restrict__ Ql,
    _Float16* __restrict__ Kh, _Float16* __restrict__ Kl,
    _Float16* __restrict__ Vv) {
  __shared__ __align__(16) char QS[49152];
  char* Wh = QS;
  char* Wl = QS + 16384;
  char* Xh = QS + 32768;
  char* Xl = QS + 40960;
  char* Thi = QS;              // epilogue reuse: [64 p][128 o] f16 = 16KB
  char* Tlo = QS + 16384;

  const int tid = threadIdx.x;
  const int lane = tid & 63;
  const int w = tid >> 6;
  const int c = lane & 15;
  const int g = lane >> 4;
  const int o0 = blockIdx.x * 128;
  const int p0 = blockIdx.y * 64;
  const int b = blockIdx.z;

  #pragma unroll
  for (int it = 0; it < 4; ++it) {
    int task = tid + it * 256;
    int oct = task & 7, o = task >> 3;
    const f4* wr = (const f4*)(wqkv + (size_t)(o0 + o) * CIN + oct * 8);
    f4 wa = wr[0], wb = wr[1];
    h8 hi, lo;
    #pragma unroll
    for (int e = 0; e < 8; ++e) {
      float v = e < 4 ? wa[e] : wb[e - 4];
      _Float16 h = (_Float16)v;
      hi[e] = h;
      lo[e] = (_Float16)((v - (float)h) * LOSCALE);
    }
    int byo = o * 128 + ((oct ^ (o & 7)) << 4);
    *(h8*)(Wh + byo) = hi;
    *(h8*)(Wl + byo) = lo;
  }
  {
    int kp = tid & 31;      // c-pair: channels 2kp, 2kp+1
    int pgrp = tid >> 5;    // p-octet 0..7
    const float* xr0 = x + ((size_t)b * CIN + 2 * kp) * NPIX + p0 + pgrp * 8;
    const float* xr1 = xr0 + NPIX;
    f4 a0 = *(const f4*)xr0, a1 = *(const f4*)(xr0 + 4);
    f4 b0 = *(const f4*)xr1, b1 = *(const f4*)(xr1 + 4);
    int oct = kp >> 2;
    int slot4 = (kp & 3) * 4;
    #pragma unroll
    for (int e = 0; e < 8; ++e) {
      float v0 = e < 4 ? a0[e] : a1[e - 4];
      float v1 = e < 4 ? b0[e] : b1[e - 4];
      _Float16 h0 = (_Float16)v0, h1 = (_Float16)v1;
      float l0f = (v0 - (float)h0) * LOSCALE;
      float l1f = (v1 - (float)h1) * LOSCALE;
      int p = pgrp * 8 + e;
      int byo = p * 128 + ((oct ^ (p & 7)) << 4) + slot4;
      union { h2 h; unsigned u; } uh, ul;
      uh.h[0] = h0; uh.h[1] = h1;
      ul.h[0] = (_Float16)l0f; ul.h[1] = (_Float16)l1f;
      *(unsigned*)(Xh + byo) = uh.u;
      *(unsigned*)(Xl + byo) = ul.u;
    }
  }
  __syncthreads();

  f4 zf = {0.f, 0.f, 0.f, 0.f};
  f4 acc[2][4], cor[2][4];
  #pragma unroll
  for (int oi = 0; oi < 2; ++oi)
    #pragma unroll
    for (int pi = 0; pi < 4; ++pi) { acc[oi][pi] = zf; cor[oi][pi] = zf; }

  const int ob = w * 32;
  #pragma unroll
  for (int kh = 0; kh < 2; ++kh) {
    h8 ah[2], al[2], bh[4], bl[4];
    #pragma unroll
    for (int oi = 0; oi < 2; ++oi) {
      int orow = ob + ((c >> 2) << 3) + (c & 3) + oi * 4;
      int ch = (((kh * 4 + g) ^ (orow & 7)) << 4);
      ah[oi] = *(const h8*)(Wh + orow * 128 + ch);
      al[oi] = *(const h8*)(Wl + orow * 128 + ch);
    }
    #pragma unroll
    for (int pi = 0; pi < 4; ++pi) {
      int prow = pi * 16 + c;
      int ch = (((kh * 4 + g) ^ (prow & 7)) << 4);
      bh[pi] = *(const h8*)(Xh + prow * 128 + ch);
      bl[pi] = *(const h8*)(Xl + prow * 128 + ch);
    }
    __builtin_amdgcn_s_setprio(1);
    #pragma unroll
    for (int oi = 0; oi < 2; ++oi)
      #pragma unroll
      for (int pi = 0; pi < 4; ++pi) {
        acc[oi][pi] = __builtin_amdgcn_mfma_f32_16x16x32_f16(ah[oi], bh[pi], acc[oi][pi], 0, 0, 0);
        cor[oi][pi] = __builtin_amdgcn_mfma_f32_16x16x32_f16(ah[oi], bl[pi], cor[oi][pi], 0, 0, 0);
        cor[oi][pi] = __builtin_amdgcn_mfma_f32_16x16x32_f16(al[oi], bh[pi], cor[oi][pi], 0, 0, 0);
      }
    __builtin_amdgcn_s_setprio(0);
  }

  const int part = o0 >> 9;
  const float scl = part == 0 ? QSCALE : 1.0f;
  _Float16* dsth = part == 0 ? Qh : (part == 1 ? Kh : Vv);
  _Float16* dstl = part == 0 ? Ql : (part == 1 ? Kl : nullptr);

  __syncthreads();   // all LDS operand reads done; reuse QS for output tile
  // ---- stage result into LDS [p][o-local], chunk-XOR swizzled ----
  {
    const int chunk = 4 * w + g;          // o-local 16B-chunk = (w*32+8g)/8
    #pragma unroll
    for (int pi = 0; pi < 4; ++pi) {
      int p = pi * 16 + c;
      h8 hv, lv;
      #pragma unroll
      for (int oi = 0; oi < 2; ++oi)
        #pragma unroll
        for (int reg = 0; reg < 4; ++reg) {
          float v = (acc[oi][pi][reg] + cor[oi][pi][reg] * INV_LOSCALE) * scl;
          _Float16 hh = (_Float16)v;
          hv[oi * 4 + reg] = hh;
          lv[oi * 4 + reg] = (_Float16)(v - (float)hh);   // UNSCALED residual
        }
      int byo = p * 256 + ((chunk ^ (p & 15)) << 4);
      *(h8*)(Thi + byo) = hv;
      if (dstl) *(h8*)(Tlo + byo) = lv;
    }
  }
  __syncthreads();
  // ---- coalesced store: 8 lanes cover one 128B (bh,p) row ----
  #pragma unroll
  for (int it = 0; it < 4; ++it) {
    int task = tid + it * 256;   // 1024 tasks
    int p = task >> 4;           // 0..63
    int ck = task & 15;          // 16B chunk within [128 o]
    int byo = p * 256 + ((ck ^ (p & 15)) << 4);
    int o = o0 + ck * 8;
    int h = (o >> 6) & 7;
    int d = o & 63;
    size_t off = (((size_t)(b * NH + h)) * NPIX + p0 + p) * DH + d;
    h8 v = *(const h8*)(Thi + byo);
    *(h8*)(dsth + off) = v;
    if (dstl) {
      h8 v2 = *(const h8*)(Tlo + byo);
      *(h8*)(dstl + off) = v2;
    }
  }
}

// ---------------- fused MFMA attention: 32x32x16, P in registers ----------
// Wave w owns rows i = w*32 + (lane&31); k/j slot = lane>>5.
// LDS (56KB): KH[2] 0..16K | KL[2] 16K..32K | VB[2] 32K..48K |
//             LHc 48K..56K ([16 t][128 rows][2] fp16).
__global__ __launch_bounds__(256, 2) void attn_mfma(
    const _Float16* __restrict__ Qh, const _Float16* __restrict__ Ql,
    const _Float16* __restrict__ Kh, const _Float16* __restrict__ Kl,
    const _Float16* __restrict__ V,
    const float* __restrict__ rel_h, const float* __restrict__ rel_w,
    float* __restrict__ out) {
  __shared__ __align__(16) char SMem[57344];
  _Float16* LHc = (_Float16*)(SMem + 49152);  // [16 t][128 rows][2] fp16
  _Float16* LWT = (_Float16*)(SMem + 32768);  // prologue temp [128][64]
  float* OT = (float*)SMem;                   // epilogue [64][128] f32

  const int tid = threadIdx.x;
  const int lane = tid & 63;
  const int w = tid >> 6;
  const int wu = __builtin_amdgcn_readfirstlane(w);
  const int c = lane & 15;
  const int g = lane >> 4;
  const int il = lane & 31;
  const int hi = lane >> 5;
  const int bx = blockIdx.x;
  const int bh = ((bx & 7) << 3) | ((bx >> 3) & 7);
  const int i0 = (bx >> 6) << 7;

  const _Float16* Qhg = Qh + (size_t)bh * NPIX * DH;
  const _Float16* Qlg = Ql + (size_t)bh * NPIX * DH;
  const _Float16* Khg = Kh + (size_t)bh * NPIX * DH;
  const _Float16* Klg = Kl + (size_t)bh * NPIX * DH;
  const _Float16* Vg  = V  + (size_t)bh * NPIX * DH;

  // prologue Q fragments (16x16 B operand)
  const h8* Qr0h = (const h8*)(Qhg + (size_t)(i0 + w * 32 + c) * DH);
  const h8* Qr0l = (const h8*)(Qlg + (size_t)(i0 + w * 32 + c) * DH);
  const h8* Qr1h = (const h8*)(Qhg + (size_t)(i0 + w * 32 + 16 + c) * DH);
  const h8* Qr1l = (const h8*)(Qlg + (size_t)(i0 + w * 32 + 16 + c) * DH);
  h8 q0h[2] = {Qr0h[g], Qr0h[4 + g]};
  h8 q0l[2] = {Qr0l[g], Qr0l[4 + g]};
  h8 q1h[2] = {Qr1h[g], Qr1h[4 + g]};
  h8 q1l[2] = {Qr1l[g], Qr1l[4 + g]};

  // K staging offsets (pre-swizzled global source, linear LDS dest)
  const int s0i = wu * 128 + lane;
  const int s1i = s0i + 64;
  const int ko0 = (s0i >> 3) * 128 + (((s0i & 7) ^ ((s0i >> 3) & 7)) << 4);
  const int ko1 = (s1i >> 3) * 128 + (((s1i & 7) ^ ((s1i >> 3) & 7)) << 4);

  // ---- stage rel tables: rel_h -> KH0, rel_w -> KL0 ----
  #pragma unroll
  for (int it = 0; it < 2; ++it) {
    int task = tid + it * 256;
    int oct = task & 7, s = task >> 3;
    int ss = s < 63 ? s : 62;
    const float* sh = rel_h + (size_t)ss * DH + oct * 8;
    const float* sw = rel_w + (size_t)ss * DH + oct * 8;
    h8 hh, ww;
    #pragma unroll
    for (int e = 0; e < 8; ++e) {
      hh[e] = (_Float16)sh[e];
      ww[e] = (_Float16)sw[e];
    }
    int byo = s * 128 + ((oct ^ (s & 7)) << 4);
    *(h8*)(SMem + byo) = hh;
    *(h8*)(SMem + 16384 + byo) = ww;
  }
  __syncthreads();

  // ---- lh/lw tables via swapped 16x16 MFMA (lo folded into same acc) ----
  const int yi = (i0 + w * 32) >> 5;
  f4 zf = {0.f, 0.f, 0.f, 0.f};
  #pragma unroll
  for (int rs = 0; rs < 2; ++rs) {
    f4 lhD[4], lwD[4];
    #pragma unroll
    for (int st = 0; st < 4; ++st) { lhD[st] = zf; lwD[st] = zf; }
    #pragma unroll
    for (int kh = 0; kh < 2; ++kh) {
      h8 bq = rs ? q1h[kh] : q0h[kh];
      h8 bl = rs ? q1l[kh] : q0l[kh];
      #pragma unroll
      for (int st = 0; st < 4; ++st) {
        int srow = st * 16 + c;
        int chb = srow * 128 + (((kh * 4 + g) ^ (srow & 7)) << 4);
        h8 ra = *(const h8*)(SMem + chb);
        h8 wa = *(const h8*)(SMem + 16384 + chb);
        lhD[st] = __builtin_amdgcn_mfma_f32_16x16x32_f16(ra, bq, lhD[st], 0, 0, 0);
        lhD[st] = __builtin_amdgcn_mfma_f32_16x16x32_f16(ra, bl, lhD[st], 0, 0, 0);
        lwD[st] = __builtin_amdgcn_mfma_f32_16x16x32_f16(wa, bq, lwD[st], 0, 0, 0);
        lwD[st] = __builtin_amdgcn_mfma_f32_16x16x32_f16(wa, bl, lwD[st], 0, 0, 0);
      }
    }
    int lrow = w * 32 + rs * 16 + c;
    #pragma unroll
    for (int st = 0; st < 4; ++st)
      #pragma unroll
      for (int reg = 0; reg < 4; ++reg) {
        int s = st * 16 + 4 * g + reg;
        int k = s - 31 + yi;
        if (k >= 0 && k < 32)
          LHc[(k >> 1) * 256 + lrow * 2 + (k & 1)] = (_Float16)lhD[st][reg];
        LWT[lrow * 64 + s] = (_Float16)lwD[st][reg];
      }
  }
  __syncthreads();

  // lwp[reg]: lw[i][31 + jl(reg) - il], jl = (reg&3)+8*(reg>>2)+4*hi
  float lwp[16];
  {
    int r = w * 32 + il;
    #pragma unroll
    for (int reg = 0; reg < 16; ++reg) {
      int jl = (reg & 3) + 8 * (reg >> 2) + 4 * hi;
      lwp[reg] = (float)LWT[r * 64 + 31 + jl - il];
    }
  }
  // main-loop Q fragments (32x32 B operand: col = il, k-slot = hi)
  const h8* Qmh = (const h8*)(Qhg + (size_t)(i0 + w * 32 + il) * DH);
  const h8* Qml = (const h8*)(Qlg + (size_t)(i0 + w * 32 + il) * DH);
  h8 qmh[4], qml[4];
  #pragma unroll
  for (int kb = 0; kb < 4; ++kb) {
    qmh[kb] = Qmh[2 * kb + hi];
    qml[kb] = Qml[2 * kb + hi];
  }
  __syncthreads();

  // ---- stage tile 0 ----
  {
    gload_lds16((const char*)Khg + ko0, SMem + wu * 2048);
    gload_lds16((const char*)Khg + ko1, SMem + wu * 2048 + 1024);
    gload_lds16((const char*)Klg + ko0, SMem + 16384 + wu * 2048);
    gload_lds16((const char*)Klg + ko1, SMem + 16384 + wu * 2048 + 1024);
    int jp = tid & 31, dd = tid >> 5;
    const h8* vr = (const h8*)(Vg + (size_t)(2 * jp) * DH);
    h8 v0 = vr[dd], v1 = vr[8 + dd];
    us8 u0 = *(const us8*)&v0, u1 = *(const us8*)&v1;
    #pragma unroll
    for (int e = 0; e < 8; ++e) {
      int d = dd * 8 + e;
      unsigned int val = (unsigned int)u0[e] | ((unsigned int)u1[e] << 16);
      *(unsigned int*)(SMem + 32768 + d * 128 + (((jp >> 2) ^ (d & 7)) << 4) + (jp & 3) * 4) = val;
    }
  }
  __syncthreads();

  float m_s = -1e30f, lp = 0.f;
  f16v O0, O1;
  #pragma unroll
  for (int e = 0; e < 16; ++e) { O0[e] = 0.f; O1[e] = 0.f; }

  const int swl = (il & 7);
  int cur = 0;
  #pragma unroll 1
  for (int t = 0; t < 16; ++t) {
    char* Kc  = SMem + cur * 8192;
    char* KLc = SMem + 16384 + cur * 8192;
    char* Vc  = SMem + 32768 + cur * 8192;
    const int nxt = cur ^ 1;
    const bool pre = t < 15;
    const int jp = tid & 31, dd = tid >> 5;
    h8 v0 = {}, v1 = {};
    if (pre) {
      const char* kg  = (const char*)Khg + (size_t)(t + 1) * 8192;
      const char* klg = (const char*)Klg + (size_t)(t + 1) * 8192;
      gload_lds16(kg + ko0, SMem + nxt * 8192 + wu * 2048);
      gload_lds16(kg + ko1, SMem + nxt * 8192 + wu * 2048 + 1024);
      gload_lds16(klg + ko0, SMem + 16384 + nxt * 8192 + wu * 2048);
      gload_lds16(klg + ko1, SMem + 16384 + nxt * 8192 + wu * 2048 + 1024);
      const h8* vr = (const h8*)(Vg + (size_t)((t + 1) * 64 + 2 * jp) * DH);
      v0 = vr[dd];
      v1 = vr[8 + dd];
    }

    // ---- QK^T swapped 32x32x16: S rows j, col i = il ----
    f16v S0, S1;
    #pragma unroll
    for (int e = 0; e < 16; ++e) { S0[e] = 0.f; S1[e] = 0.f; }
    #pragma unroll
    for (int kb = 0; kb < 4; ++kb) {
      int chb0 = il * 128 + (((2 * kb + hi) ^ swl) << 4);
      int chb1 = chb0 + 32 * 128;
      h8 a0h = *(const h8*)(Kc + chb0);
      h8 a0l = *(const h8*)(KLc + chb0);
      h8 a1h = *(const h8*)(Kc + chb1);
      h8 a1l = *(const h8*)(KLc + chb1);
      __builtin_amdgcn_s_setprio(1);
      S0 = __builtin_amdgcn_mfma_f32_32x32x16_f16(a0h, qmh[kb], S0, 0, 0, 0);
      S0 = __builtin_amdgcn_mfma_f32_32x32x16_f16(a0l, qmh[kb], S0, 0, 0, 0);
      S0 = __builtin_amdgcn_mfma_f32_32x32x16_f16(a0h, qml[kb], S0, 0, 0, 0);
      S1 = __builtin_amdgcn_mfma_f32_32x32x16_f16(a1h, qmh[kb], S1, 0, 0, 0);
      S1 = __builtin_amdgcn_mfma_f32_32x32x16_f16(a1l, qmh[kb], S1, 0, 0, 0);
      S1 = __builtin_amdgcn_mfma_f32_32x32x16_f16(a1h, qml[kb], S1, 0, 0, 0);
      __builtin_amdgcn_s_setprio(0);
    }

    // ---- finish: bias + online softmax + in-register P fragments ----
    h8 fr[4];
    {
      int r = w * 32 + il;
      h2 lhu = *(const h2*)(LHc + t * 256 + r * 2);
      float lh0 = (float)lhu[0], lh1 = (float)lhu[1];
      #pragma unroll
      for (int reg = 0; reg < 16; ++reg) {
        S0[reg] += lwp[reg] + lh0;
        S1[reg] += lwp[reg] + lh1;
      }
      float v8[8];
      #pragma unroll
      for (int e = 0; e < 8; ++e)
        v8[e] = fmaxf(fmaxf(S0[e], S0[e + 8]), fmaxf(S1[e], S1[e + 8]));
      float w0 = fmaxf(fmaxf(v8[0], v8[1]), fmaxf(v8[2], v8[3]));
      float w1 = fmaxf(fmaxf(v8[4], v8[5]), fmaxf(v8[6], v8[7]));
      float mx = fmaxf(w0, w1);
      mx = fmaxf(mx, __shfl_xor(mx, 32, 64));
      bool sk = mx <= m_s + DTHR;      // T13 defer-max
      if (!__all(sk)) {
        float mn = fmaxf(m_s, mx);
        float corr = fexp2(m_s - mn);
        m_s = mn;
        lp *= corr;
        #pragma unroll
        for (int e = 0; e < 16; ++e) { O0[e] *= corr; O1[e] *= corr; }
      }
      float pv0[16], pv1[16];
      float sum = 0.f;
      #pragma unroll
      for (int e = 0; e < 16; ++e) {
        pv0[e] = fexp2(S0[e] - m_s);
        pv1[e] = fexp2(S1[e] - m_s);
        sum += pv0[e] + pv1[e];
      }
      lp += sum;
      // T12: build PV B-operand fragments in-register (no LDS round-trip).
      // jkb uses pv[8*jp0 .. 8*jp0+7]; swap fills partner half-slots.
      #pragma unroll
      for (int jkb = 0; jkb < 4; ++jkb) {
        const float* pv = (jkb < 2) ? pv0 : pv1;
        int base = (jkb & 1) * 8;
        unsigned x01 = pk16(pv[base + 0], pv[base + 1]);
        unsigned x23 = pk16(pv[base + 2], pv[base + 3]);
        unsigned y01 = pk16(pv[base + 4], pv[base + 5]);
        unsigned y23 = pk16(pv[base + 6], pv[base + 7]);
        i2v r1 = __builtin_amdgcn_permlane32_swap((int)x01, (int)y01, false, false);
        i2v r2 = __builtin_amdgcn_permlane32_swap((int)x23, (int)y23, false, false);
        union { unsigned u[4]; h8 h; } fu;
        fu.u[0] = (unsigned)r1[0];
        fu.u[1] = (unsigned)r2[0];
        fu.u[2] = (unsigned)r1[1];
        fu.u[3] = (unsigned)r2[1];
        fr[jkb] = fu.h;
      }
    }

    // ---- PV swapped 32x32x16: A=V (LDS), B=P (registers) ----
    #pragma unroll
    for (int jkb = 0; jkb < 4; ++jkb) {
      int och = (((2 * jkb + hi) ^ swl) << 4);
      __builtin_amdgcn_s_setprio(1);
      h8 av0 = *(const h8*)(Vc + il * 128 + och);
      h8 av1 = *(const h8*)(Vc + (32 + il) * 128 + och);
      O0 = __builtin_amdgcn_mfma_f32_32x32x16_f16(av0, fr[jkb], O0, 0, 0, 0);
      O1 = __builtin_amdgcn_mfma_f32_32x32x16_f16(av1, fr[jkb], O1, 0, 0, 0);
      __builtin_amdgcn_s_setprio(0);
    }

    if (pre) {   // T14: write prefetched V after compute
      us8 u0 = *(const us8*)&v0, u1 = *(const us8*)&v1;
      char* Vn = SMem + 32768 + nxt * 8192;
      #pragma unroll
      for (int e = 0; e < 8; ++e) {
        int d = dd * 8 + e;
        unsigned int val = (unsigned int)u0[e] | ((unsigned int)u1[e] << 16);
        *(unsigned int*)(Vn + d * 128 + (((jp >> 2) ^ (d & 7)) << 4) + (jp & 3) * 4) = val;
      }
    }
    __syncthreads();
    cur = nxt;
  }

  // ---- epilogue: reduce l across hi, normalize, transpose, store ----
  float lt = lp + __shfl_xor(lp, 32, 64);
  float rr = __builtin_amdgcn_rcpf(lt);
  {
    int r = w * 32 + il;
    #pragma unroll
    for (int reg = 0; reg < 16; ++reg) {
      int dl = (reg & 3) + 8 * (reg >> 2) + 4 * hi;
      int d0 = dl;
      int d1 = 32 + dl;
      OT[d0 * 128 + (r ^ ((d0 & 7) << 3))] = O0[reg] * rr;
      OT[d1 * 128 + (r ^ ((d1 & 7) << 3))] = O1[reg] * rr;
    }
  }
  __syncthreads();
  #pragma unroll
  for (int it = 0; it < 8; ++it) {
    int task = tid + it * 256;
    int rq = task & 31, d = task >> 5;
    f4 vv = *(const f4*)&OT[d * 128 + ((rq * 4) ^ ((d & 7) << 3))];
    *(f4*)(out + (((size_t)bh * 64 + d) << 10) + i0 + rq * 4) = vv;
  }
}

extern "C" void kernel_launch(void* const* d_in, const int* in_sizes, int n_in,
                              void* d_out, int out_size, void* d_ws, size_t ws_size,
                              hipStream_t stream) {
  const float* x  = (const float*)d_in[0];
  const float* wq = (const float*)d_in[1];
  const float* rh = (const float*)d_in[2];
  const float* rw = (const float*)d_in[3];
  float* out = (float*)d_out;

  const size_t sz = (size_t)NBH * NPIX * DH;
  _Float16* Qh = (_Float16*)d_ws;
  _Float16* Ql = Qh + sz;
  _Float16* Kh = Ql + sz;
  _Float16* Kl = Kh + sz;
  _Float16* V  = Kl + sz;

  qkv_mfma<<<dim3(12, 16, 8), 256, 0, stream>>>(x, wq, Qh, Ql, Kh, Kl, V);
  attn_mfma<<<dim3(512), 256, 0, stream>>>(Qh, Ql, Kh, Kl, V, rh, rw, out);
}